// Round 3
// baseline (1764.065 us; speedup 1.0000x reference)
//
#include <hip/hip_runtime.h>

// ---------------------------------------------------------------------------
// RelPartialLearnableMultiHeadAttn (Transformer-XL attention), MI355X fp32.
//
// Pipeline:
//   k_proj : w@Wqkv -> Q/K/V head-major layouts ; r@Wr -> rke (reversed rows)
//   k_bias : bk[b,n,j] = r_w_bias[n]·K[b,n,j] ; brd[n,d] = r_r_bias[n]·rke[n,d]
//   k_attn : flash attention, S = SCALE*(q·k_j + q·rke_{i-j} + bk[j] + brd[i-j])
//   k_wo   : attn_vec@Wo + residual(w)
//   k_ln   : LayerNorm
//
// rel_shift identity (causal region only, which is all that survives the mask):
//   BD_shifted[i,j] = (q_i + r_r_bias)·r_head_k[N-1-(i-j)]  =: qb_i·rke[i-j]
// ---------------------------------------------------------------------------

// workspace layout in floats (total 34M floats = ~136 MB)
#define OFF_Q   0u                       // [8][16][1024][64] 8M
#define OFF_K   (8u<<20)                 // 8M
#define OFF_V   (16u<<20)                // 8M
#define OFF_RKE (24u<<20)                // [16][1024][64] 1M
#define OFF_BK  (25u<<20)                // [8][16][1024] 128K
#define OFF_BRD ((25u<<20) + (1u<<17))   // [16][1088] (64 zero-pad + 1024)
#define OFF_AV  (26u<<20)                // [1024][8][1024] 8M
#define OFF_TMP 0u                       // aliases Q (dead after attention)

// ---------------- projection GEMM: qkv (by<64) and r (by>=64) ----------------
__global__ __launch_bounds__(256) void k_proj(const float* __restrict__ Wm,
                                              const float* __restrict__ Rm,
                                              const float* __restrict__ Bq,
                                              const float* __restrict__ Br,
                                              float* __restrict__ ws) {
  const int bx = blockIdx.x, by = blockIdx.y;
  const bool isr = by >= 64;
  if (isr && bx >= 8) return;
  const float* A = isr ? Rm : Wm;
  const float* B = isr ? Br : Bq;
  const int ldb = isr ? 1024 : 3072;
  const int m0 = (isr ? (by - 64) : by) * 128;
  const int n0 = bx * 128;

  __shared__ float AsT[16][132];  // [k][m], padded
  __shared__ float Bs[16][132];   // [k][n]

  const int tid = threadIdx.x;
  const int ty = tid >> 4, tx = tid & 15;
  const int a_row = tid >> 2;         // 0..63 (+64)
  const int a_kc  = (tid & 3) << 2;   // 0,4,8,12
  const int b_k   = tid >> 5;         // 0..7 (+8)
  const int b_col = (tid & 31) << 2;  // 0..124

  float acc[2][2][4][4];
#pragma unroll
  for (int p = 0; p < 2; ++p)
#pragma unroll
    for (int q = 0; q < 2; ++q)
#pragma unroll
      for (int i = 0; i < 4; ++i)
#pragma unroll
        for (int j = 0; j < 4; ++j) acc[p][q][i][j] = 0.f;

  for (int k0 = 0; k0 < 1024; k0 += 16) {
    float4 av0 = *(const float4*)&A[(size_t)(m0 + a_row) * 1024 + k0 + a_kc];
    float4 av1 = *(const float4*)&A[(size_t)(m0 + a_row + 64) * 1024 + k0 + a_kc];
    float4 bv0 = *(const float4*)&B[(size_t)(k0 + b_k) * ldb + n0 + b_col];
    float4 bv1 = *(const float4*)&B[(size_t)(k0 + b_k + 8) * ldb + n0 + b_col];
    __syncthreads();
    AsT[a_kc + 0][a_row] = av0.x;  AsT[a_kc + 1][a_row] = av0.y;
    AsT[a_kc + 2][a_row] = av0.z;  AsT[a_kc + 3][a_row] = av0.w;
    AsT[a_kc + 0][a_row + 64] = av1.x;  AsT[a_kc + 1][a_row + 64] = av1.y;
    AsT[a_kc + 2][a_row + 64] = av1.z;  AsT[a_kc + 3][a_row + 64] = av1.w;
    *(float4*)&Bs[b_k][b_col] = bv0;
    *(float4*)&Bs[b_k + 8][b_col] = bv1;
    __syncthreads();
#pragma unroll
    for (int k = 0; k < 16; ++k) {
      float4 a0 = *(const float4*)&AsT[k][ty << 2];
      float4 a1 = *(const float4*)&AsT[k][64 + (ty << 2)];
      float4 b0 = *(const float4*)&Bs[k][tx << 2];
      float4 b1 = *(const float4*)&Bs[k][64 + (tx << 2)];
      float aa[2][4] = {{a0.x, a0.y, a0.z, a0.w}, {a1.x, a1.y, a1.z, a1.w}};
      float bb[2][4] = {{b0.x, b0.y, b0.z, b0.w}, {b1.x, b1.y, b1.z, b1.w}};
#pragma unroll
      for (int p = 0; p < 2; ++p)
#pragma unroll
        for (int q = 0; q < 2; ++q)
#pragma unroll
          for (int i = 0; i < 4; ++i)
#pragma unroll
            for (int j = 0; j < 4; ++j)
              acc[p][q][i][j] += aa[p][i] * bb[q][j];
    }
  }

#pragma unroll
  for (int p = 0; p < 2; ++p) {
#pragma unroll
    for (int q = 0; q < 2; ++q) {
      const int cbase = n0 + (q << 6) + (tx << 2);
#pragma unroll
      for (int i = 0; i < 4; ++i) {
        const int m = m0 + (p << 6) + (ty << 2) + i;
        float4 v = make_float4(acc[p][q][i][0], acc[p][q][i][1],
                               acc[p][q][i][2], acc[p][q][i][3]);
        if (!isr) {
          const int qq = m >> 3, b = m & 7;                 // m = q*8 + b
          const int s = cbase >> 10, hd = (cbase >> 6) & 15, dh = cbase & 63;
          const unsigned base = (s == 0) ? OFF_Q : (s == 1) ? OFF_K : OFF_V;
          *(float4*)&ws[base + (((((b << 4) + hd) << 10) + qq) << 6) + dh] = v;
        } else {
          const int n = (cbase >> 6) & 15, dh = cbase & 63;
          // reversed row: rke[d] = rk[1023-d]  ->  row m stores at d = 1023-m
          *(float4*)&ws[OFF_RKE + (((n << 10) + (1023 - m)) << 6) + dh] = v;
        }
      }
    }
  }
}

// ---------------- rank-1 bias dot precompute ----------------
__global__ __launch_bounds__(256) void k_bias(const float* __restrict__ rwb,
                                              const float* __restrict__ rrb,
                                              float* __restrict__ ws) {
  const int t = blockIdx.x * 256 + threadIdx.x;
  if (t < 131072) {                       // bk[b,n,j] = rwb[n]·K[b,n,j]
    const int j = t & 1023, bn = t >> 10, n = bn & 15;
    const float* kr = ws + OFF_K + ((((size_t)bn << 10) + j) << 6);
    const float* br = rwb + (n << 6);
    float s = 0.f;
#pragma unroll
    for (int d = 0; d < 64; d += 4) {
      float4 kv = *(const float4*)&kr[d];
      float4 bv = *(const float4*)&br[d];
      s += kv.x * bv.x + kv.y * bv.y + kv.z * bv.z + kv.w * bv.w;
    }
    ws[OFF_BK + t] = s;
  } else if (t < 147456) {                // brd[n,d] = rrb[n]·rke[n,d]
    const int u = t - 131072;
    const int d = u & 1023, n = u >> 10;
    const float* rr = ws + OFF_RKE + ((((size_t)n << 10) + d) << 6);
    const float* br = rrb + (n << 6);
    float s = 0.f;
#pragma unroll
    for (int dd = 0; dd < 64; dd += 4) {
      float4 kv = *(const float4*)&rr[dd];
      float4 bv = *(const float4*)&br[dd];
      s += kv.x * bv.x + kv.y * bv.y + kv.z * bv.z + kv.w * bv.w;
    }
    ws[OFF_BRD + n * 1088 + 64 + d] = s;
  } else if (t < 148480) {                // zero-pad brd for d<0 (masked region)
    const int u = t - 147456;
    ws[OFF_BRD + (u >> 6) * 1088 + (u & 63)] = 0.f;
  }
}

// ---------------- fused causal flash attention with Toeplitz rel-band ----------------
__global__ __launch_bounds__(256) void k_attn(float* __restrict__ ws) {
  __shared__ float qT[64][64];    // qT[dh][ti], XOR-swizzled cols (persistent)
  __shared__ float pool[12288];   // score: kT[64][64] + band[64][128]; PV: Ps[64][68] + Vs[64][68]

  const int tid = threadIdx.x;
  const int it = blockIdx.x;      // query tile
  const int bn = blockIdx.y;      // b*16 + n
  const int b = bn >> 4, n = bn & 15;
  const int i0 = it << 6;
  const float* Q   = ws + OFF_Q   + ((size_t)bn << 16);
  const float* K   = ws + OFF_K   + ((size_t)bn << 16);
  const float* V   = ws + OFF_V   + ((size_t)bn << 16);
  const float* RKE = ws + OFF_RKE + ((size_t)n << 16);
  const float* BKv = ws + OFF_BK  + (bn << 10);
  const float* BRD = ws + OFF_BRD + n * 1088;

  const int rg = tid >> 4, cg = tid & 15;   // 16x16 threads; 4x4 micro
  const int Dg = rg - cg;                   // tile-relative diag offset

  // Q tile -> LDS transposed, col ^= ((dh>>2)&7)<<2
#pragma unroll
  for (int rep = 0; rep < 4; ++rep) {
    const int f = tid + (rep << 8);
    const int row = f >> 4;
    const int dh0 = (f & 15) << 2;
    float4 v = *(const float4*)&Q[((i0 + row) << 6) + dh0];
    const int col = row ^ (((dh0 >> 2) & 7) << 2);
    qT[dh0 + 0][col] = v.x;  qT[dh0 + 1][col] = v.y;
    qT[dh0 + 2][col] = v.z;  qT[dh0 + 3][col] = v.w;
  }

  float O[4][4];
  float m_r[4], l_r[4];
#pragma unroll
  for (int a = 0; a < 4; ++a) {
    m_r[a] = -3.0e38f;
    l_r[a] = 0.f;
#pragma unroll
    for (int d = 0; d < 4; ++d) O[a][d] = 0.f;
  }

  float* kT   = pool;           // [64][64]  swizzled
  float* band = pool + 4096;    // [64][128] swizzled; band col bd = d - dbase + 63
  float* Ps   = pool;           // [64][68]  (PV phase, row-major P)
  float* Vs   = pool + 4352;    // [64][68]

  for (int jt = 0; jt <= it; ++jt) {
    const int j0 = jt << 6;
    const int dbase = i0 - j0;

    // K tile -> kT (transposed+swizzled)
#pragma unroll
    for (int rep = 0; rep < 4; ++rep) {
      const int f = tid + (rep << 8);
      const int row = f >> 4;
      const int dh0 = (f & 15) << 2;
      float4 v = *(const float4*)&K[((j0 + row) << 6) + dh0];
      const int col = row ^ (((dh0 >> 2) & 7) << 2);
      kT[((dh0 + 0) << 6) + col] = v.x;  kT[((dh0 + 1) << 6) + col] = v.y;
      kT[((dh0 + 2) << 6) + col] = v.z;  kT[((dh0 + 3) << 6) + col] = v.w;
    }
    // rke band rows d in [dbase-63, dbase+64] -> band (transposed+swizzled), OOB=0
#pragma unroll
    for (int rep = 0; rep < 8; ++rep) {
      const int f = tid + (rep << 8);
      const int bd = f >> 4;
      const int dh0 = (f & 15) << 2;
      const int d = dbase + bd - 63;
      float4 v = make_float4(0.f, 0.f, 0.f, 0.f);
      if (d >= 0 && d < 1024) v = *(const float4*)&RKE[(d << 6) + dh0];
      const int col = bd ^ (((dh0 >> 2) & 7) << 2);
      band[((dh0 + 0) << 7) + col] = v.x;  band[((dh0 + 1) << 7) + col] = v.y;
      band[((dh0 + 2) << 7) + col] = v.z;  band[((dh0 + 3) << 7) + col] = v.w;
    }
    __syncthreads();

    // S = q·(k + rke_band): AC and BD fused into one FMA per (a,c,dh)
    float S[4][4];
#pragma unroll
    for (int a = 0; a < 4; ++a)
#pragma unroll
      for (int c = 0; c < 4; ++c) S[a][c] = 0.f;

#pragma unroll 4
    for (int dh = 0; dh < 64; ++dh) {
      const int sw = (dh >> 2) & 7;
      float4 qv = *(const float4*)&qT[dh][(rg ^ sw) << 2];
      float4 kv = *(const float4*)&kT[(dh << 6) + ((cg ^ sw) << 2)];
      float4 r0 = *(const float4*)&band[(dh << 7) + (((15 + Dg) ^ sw) << 2)];
      float4 r1 = *(const float4*)&band[(dh << 7) + (((16 + Dg) ^ sw) << 2)];
      float qa[4] = {qv.x, qv.y, qv.z, qv.w};
      float kk[4] = {kv.x, kv.y, kv.z, kv.w};
      float rr[8] = {r0.x, r0.y, r0.z, r0.w, r1.x, r1.y, r1.z, r1.w};
#pragma unroll
      for (int a = 0; a < 4; ++a)
#pragma unroll
        for (int c = 0; c < 4; ++c)
          S[a][c] += qa[a] * (kk[c] + rr[3 + a - c]);  // bd = 63+4Dg+a-c -> rr[3+a-c]
    }

    // + rank-1 bias terms, scale, causal mask on diagonal tile
    float4 bkv = *(const float4*)&BKv[j0 + (cg << 2)];
    const int dB = 64 + dbase + (Dg << 2);
    float4 q0 = *(const float4*)&BRD[dB - 4];
    float4 q1 = *(const float4*)&BRD[dB];
    float bB[8] = {q0.x, q0.y, q0.z, q0.w, q1.x, q1.y, q1.z, q1.w};
    float bkk[4] = {bkv.x, bkv.y, bkv.z, bkv.w};
#pragma unroll
    for (int a = 0; a < 4; ++a)
#pragma unroll
      for (int c = 0; c < 4; ++c) {
        float s = 0.125f * (S[a][c] + bkk[c] + bB[4 + a - c]);
        if (dbase == 0 && ((rg << 2) + a) < ((cg << 2) + c)) s = -1.0e30f;
        S[a][c] = s;
      }

    // online softmax (rows owned by 16 consecutive lanes -> shfl_xor reduce)
#pragma unroll
    for (int a = 0; a < 4; ++a) {
      float mt = fmaxf(fmaxf(S[a][0], S[a][1]), fmaxf(S[a][2], S[a][3]));
      mt = fmaxf(mt, __shfl_xor(mt, 1));
      mt = fmaxf(mt, __shfl_xor(mt, 2));
      mt = fmaxf(mt, __shfl_xor(mt, 4));
      mt = fmaxf(mt, __shfl_xor(mt, 8));
      const float mnew = fmaxf(m_r[a], mt);
      const float sc = __expf(m_r[a] - mnew);
      m_r[a] = mnew;
      float rs = 0.f;
#pragma unroll
      for (int c = 0; c < 4; ++c) {
        const float p = __expf(S[a][c] - mnew);
        S[a][c] = p;
        rs += p;
      }
      rs += __shfl_xor(rs, 1);
      rs += __shfl_xor(rs, 2);
      rs += __shfl_xor(rs, 4);
      rs += __shfl_xor(rs, 8);
      l_r[a] = l_r[a] * sc + rs;
#pragma unroll
      for (int d = 0; d < 4; ++d) O[a][d] *= sc;
    }

    __syncthreads();  // score-phase LDS reads complete before overwrite

    // P (row-major, thread owns its 4 rows: 4-way store banks) + V tile -> LDS
#pragma unroll
    for (int a = 0; a < 4; ++a)
      *(float4*)&Ps[((rg << 2) + a) * 68 + (cg << 2)] =
          make_float4(S[a][0], S[a][1], S[a][2], S[a][3]);
#pragma unroll
    for (int rep = 0; rep < 4; ++rep) {
      const int f = tid + (rep << 8);
      const int row = f >> 4;
      const int dh0 = (f & 15) << 2;
      *(float4*)&Vs[row * 68 + dh0] = *(const float4*)&V[((j0 + row) << 6) + dh0];
    }
    __syncthreads();

    // O += P @ V  (P rows read as broadcast float4 chunks, V 2-way)
#pragma unroll 2
    for (int tj0 = 0; tj0 < 64; tj0 += 4) {
      float4 p0 = *(const float4*)&Ps[((rg << 2) + 0) * 68 + tj0];
      float4 p1 = *(const float4*)&Ps[((rg << 2) + 1) * 68 + tj0];
      float4 p2 = *(const float4*)&Ps[((rg << 2) + 2) * 68 + tj0];
      float4 p3 = *(const float4*)&Ps[((rg << 2) + 3) * 68 + tj0];
      float4 v0 = *(const float4*)&Vs[(tj0 + 0) * 68 + (cg << 2)];
      float4 v1 = *(const float4*)&Vs[(tj0 + 1) * 68 + (cg << 2)];
      float4 v2 = *(const float4*)&Vs[(tj0 + 2) * 68 + (cg << 2)];
      float4 v3 = *(const float4*)&Vs[(tj0 + 3) * 68 + (cg << 2)];
      float pa[4][4] = {{p0.x, p0.y, p0.z, p0.w}, {p1.x, p1.y, p1.z, p1.w},
                        {p2.x, p2.y, p2.z, p2.w}, {p3.x, p3.y, p3.z, p3.w}};
      float vd[4][4] = {{v0.x, v0.y, v0.z, v0.w}, {v1.x, v1.y, v1.z, v1.w},
                        {v2.x, v2.y, v2.z, v2.w}, {v3.x, v3.y, v3.z, v3.w}};
#pragma unroll
      for (int a = 0; a < 4; ++a)
#pragma unroll
        for (int t = 0; t < 4; ++t)
#pragma unroll
          for (int d = 0; d < 4; ++d) O[a][d] += pa[a][t] * vd[t][d];
    }
    __syncthreads();  // PV reads complete before next tile's kT/band writes
  }

  // normalize and store attn_vec[q, b, n*64+dh]
#pragma unroll
  for (int a = 0; a < 4; ++a) {
    const float inv = 1.f / l_r[a];
    const int i = i0 + (rg << 2) + a;
    *(float4*)&ws[OFF_AV + (((i << 3) + b) << 10) + (n << 6) + (cg << 2)] =
        make_float4(O[a][0] * inv, O[a][1] * inv, O[a][2] * inv, O[a][3] * inv);
  }
}

// ---------------- attn_vec @ Wo + residual ----------------
__global__ __launch_bounds__(256) void k_wo(const float* __restrict__ Wo,
                                            const float* __restrict__ Wm,
                                            float* __restrict__ ws) {
  const int bx = blockIdx.x, by = blockIdx.y;
  const int m0 = by * 128, n0 = bx * 128;
  const float* A = ws + OFF_AV;
  const float* B = Wo;

  __shared__ float AsT[16][132];
  __shared__ float Bs[16][132];

  const int tid = threadIdx.x;
  const int ty = tid >> 4, tx = tid & 15;
  const int a_row = tid >> 2;
  const int a_kc  = (tid & 3) << 2;
  const int b_k   = tid >> 5;
  const int b_col = (tid & 31) << 2;

  float acc[2][2][4][4];
#pragma unroll
  for (int p = 0; p < 2; ++p)
#pragma unroll
    for (int q = 0; q < 2; ++q)
#pragma unroll
      for (int i = 0; i < 4; ++i)
#pragma unroll
        for (int j = 0; j < 4; ++j) acc[p][q][i][j] = 0.f;

  for (int k0 = 0; k0 < 1024; k0 += 16) {
    float4 av0 = *(const float4*)&A[(size_t)(m0 + a_row) * 1024 + k0 + a_kc];
    float4 av1 = *(const float4*)&A[(size_t)(m0 + a_row + 64) * 1024 + k0 + a_kc];
    float4 bv0 = *(const float4*)&B[(size_t)(k0 + b_k) * 1024 + n0 + b_col];
    float4 bv1 = *(const float4*)&B[(size_t)(k0 + b_k + 8) * 1024 + n0 + b_col];
    __syncthreads();
    AsT[a_kc + 0][a_row] = av0.x;  AsT[a_kc + 1][a_row] = av0.y;
    AsT[a_kc + 2][a_row] = av0.z;  AsT[a_kc + 3][a_row] = av0.w;
    AsT[a_kc + 0][a_row + 64] = av1.x;  AsT[a_kc + 1][a_row + 64] = av1.y;
    AsT[a_kc + 2][a_row + 64] = av1.z;  AsT[a_kc + 3][a_row + 64] = av1.w;
    *(float4*)&Bs[b_k][b_col] = bv0;
    *(float4*)&Bs[b_k + 8][b_col] = bv1;
    __syncthreads();
#pragma unroll
    for (int k = 0; k < 16; ++k) {
      float4 a0 = *(const float4*)&AsT[k][ty << 2];
      float4 a1 = *(const float4*)&AsT[k][64 + (ty << 2)];
      float4 b0 = *(const float4*)&Bs[k][tx << 2];
      float4 b1 = *(const float4*)&Bs[k][64 + (tx << 2)];
      float aa[2][4] = {{a0.x, a0.y, a0.z, a0.w}, {a1.x, a1.y, a1.z, a1.w}};
      float bb[2][4] = {{b0.x, b0.y, b0.z, b0.w}, {b1.x, b1.y, b1.z, b1.w}};
#pragma unroll
      for (int p = 0; p < 2; ++p)
#pragma unroll
        for (int q = 0; q < 2; ++q)
#pragma unroll
          for (int i = 0; i < 4; ++i)
#pragma unroll
            for (int j = 0; j < 4; ++j)
              acc[p][q][i][j] += aa[p][i] * bb[q][j];
    }
  }

#pragma unroll
  for (int p = 0; p < 2; ++p) {
#pragma unroll
    for (int q = 0; q < 2; ++q) {
      const int cb = n0 + (q << 6) + (tx << 2);
#pragma unroll
      for (int i = 0; i < 4; ++i) {
        const int m = m0 + (p << 6) + (ty << 2) + i;
        float4 wv = *(const float4*)&Wm[(size_t)m * 1024 + cb];
        float4 v = make_float4(acc[p][q][i][0] + wv.x, acc[p][q][i][1] + wv.y,
                               acc[p][q][i][2] + wv.z, acc[p][q][i][3] + wv.w);
        *(float4*)&ws[OFF_TMP + (size_t)m * 1024 + cb] = v;
      }
    }
  }
}

// ---------------- LayerNorm ----------------
__global__ __launch_bounds__(256) void k_ln(const float* __restrict__ x,
                                            const float* __restrict__ g,
                                            const float* __restrict__ bb,
                                            float* __restrict__ out) {
  const int row = blockIdx.x;
  const int tid = threadIdx.x;
  float4 v = *(const float4*)&x[(size_t)row * 1024 + (tid << 2)];
  float s = v.x + v.y + v.z + v.w;
  float q = v.x * v.x + v.y * v.y + v.z * v.z + v.w * v.w;
#pragma unroll
  for (int off = 1; off < 64; off <<= 1) {
    s += __shfl_xor(s, off);
    q += __shfl_xor(q, off);
  }
  __shared__ float ss[4], sq[4];
  if ((tid & 63) == 0) { ss[tid >> 6] = s; sq[tid >> 6] = q; }
  __syncthreads();
  const float S = ss[0] + ss[1] + ss[2] + ss[3];
  const float Q = sq[0] + sq[1] + sq[2] + sq[3];
  const float mu = S * (1.f / 1024.f);
  const float var = Q * (1.f / 1024.f) - mu * mu;
  const float rstd = rsqrtf(var + 1e-5f);
  float4 gv = *(const float4*)&g[tid << 2];
  float4 bv = *(const float4*)&bb[tid << 2];
  float4 o = make_float4((v.x - mu) * rstd * gv.x + bv.x,
                         (v.y - mu) * rstd * gv.y + bv.y,
                         (v.z - mu) * rstd * gv.z + bv.z,
                         (v.w - mu) * rstd * gv.w + bv.w);
  *(float4*)&out[(size_t)row * 1024 + (tid << 2)] = o;
}

// ---------------------------------------------------------------------------
extern "C" void kernel_launch(void* const* d_in, const int* in_sizes, int n_in,
                              void* d_out, int out_size, void* d_ws, size_t ws_size,
                              hipStream_t stream) {
  const float* w    = (const float*)d_in[0];
  const float* r    = (const float*)d_in[1];
  const float* rwb  = (const float*)d_in[2];
  const float* rrb  = (const float*)d_in[3];
  const float* Wqkv = (const float*)d_in[4];
  const float* Wr   = (const float*)d_in[5];
  const float* Wo   = (const float*)d_in[6];
  const float* lng  = (const float*)d_in[7];
  const float* lnb  = (const float*)d_in[8];
  float* out = (float*)d_out;
  float* ws  = (float*)d_ws;

  k_proj<<<dim3(24, 72), 256, 0, stream>>>(w, r, Wqkv, Wr, ws);
  k_bias<<<dim3(580), 256, 0, stream>>>(rwb, rrb, ws);
  k_attn<<<dim3(16, 128), 256, 0, stream>>>(ws);
  k_wo<<<dim3(8, 64), 256, 0, stream>>>(Wo, w, ws);
  k_ln<<<dim3(8192), 256, 0, stream>>>(ws, lng, lnb, out);
}

// Round 4
// 1295.400 us; speedup vs baseline: 1.3618x; 1.3618x over previous
//
#include <hip/hip_runtime.h>

// ---------------------------------------------------------------------------
// RelPartialLearnableMultiHeadAttn (Transformer-XL), MI355X.
// Round 4: projection + output GEMMs via split-bf16 MFMA (3-product hi/lo),
// attention core unchanged (fp32 VALU flash w/ Toeplitz rel-band).
//
// ws float-offset map (34M floats = 136MB, proven safe):
//   [0,8M)   Q  (later TMP for wo output)
//   [8,16M)  K  (after attn: WoT_h/l bf16 at float [8M,9M))
//   [16,24M) V
//   [24,25M) RKE
//   [25M..)  BK (128K), BRD (17.4K)
//   [26,34M) phase0-1: WqkvT_h/l bf16 ; phase3+: AVh/AVl bf16 (aliased)
// ---------------------------------------------------------------------------

typedef __attribute__((ext_vector_type(8))) short short8;
typedef __attribute__((ext_vector_type(4))) float f32x4;
typedef unsigned short u16;
typedef unsigned int u32;

#define OFF_Q   0u
#define OFF_K   (8u<<20)
#define OFF_V   (16u<<20)
#define OFF_RKE (24u<<20)
#define OFF_BK  (25u<<20)
#define OFF_BRD ((25u<<20) + (1u<<17))
#define OFF_TMP 0u
// ushort offsets into ws:
#define UO_WQTH (52u<<20)   // [26.0,27.5M) floats, dead after k_gemm<0>
#define UO_WQTL (55u<<20)   // [27.5,29.0M)
#define UO_AVH  (52u<<20)   // [26,30M) floats, written by k_attn (aliases WQT)
#define UO_AVL  (60u<<20)   // [30,34M)
#define UO_WOTH (16u<<20)   // [8.0,8.5M) floats (K region, dead after attn)
#define UO_WOTL (17u<<20)   // [8.5,9.0M)

__device__ __forceinline__ u16 bft(float x) { return (u16)(__float_as_uint(x) >> 16); }
__device__ __forceinline__ float bfh(float x) { return __uint_as_float(__float_as_uint(x) & 0xFFFF0000u); }

__device__ __forceinline__ void gld16(const void* g, void* s) {
  __builtin_amdgcn_global_load_lds((const __attribute__((address_space(1))) u32*)g,
                                   (__attribute__((address_space(3))) u32*)s, 16, 0, 0);
}

// ---------------- transpose + split-bf16 weight conversion ----------------
// src [1024][ldN] f32 -> oh/ol [ldN][1024] bf16 (hi, lo)
__global__ __launch_bounds__(256) void k_convT(const float* __restrict__ src, int ldN,
                                               u16* __restrict__ oh, u16* __restrict__ ol) {
  __shared__ float t[64][65];
  const int bt = blockIdx.x, kt = bt & 15, nt = bt >> 4;
  const int k0 = kt << 6, n0 = nt << 6, tid = threadIdx.x;
  const int r = tid >> 4, c4 = (tid & 15) << 2;
#pragma unroll
  for (int rep = 0; rep < 4; ++rep) {
    const int row = (rep << 4) + r;  // k index
    float4 v = *(const float4*)&src[(size_t)(k0 + row) * ldN + n0 + c4];
    t[c4 + 0][row] = v.x; t[c4 + 1][row] = v.y;
    t[c4 + 2][row] = v.z; t[c4 + 3][row] = v.w;
  }
  __syncthreads();
#pragma unroll
  for (int rep = 0; rep < 4; ++rep) {
    const int n = (rep << 4) + r;
    float x0 = t[n][c4 + 0], x1 = t[n][c4 + 1], x2 = t[n][c4 + 2], x3 = t[n][c4 + 3];
    uint2 hv, lv;
    hv.x = (u32)bft(x0) | ((u32)bft(x1) << 16);
    hv.y = (u32)bft(x2) | ((u32)bft(x3) << 16);
    lv.x = (u32)bft(x0 - bfh(x0)) | ((u32)bft(x1 - bfh(x1)) << 16);
    lv.y = (u32)bft(x2 - bfh(x2)) | ((u32)bft(x3 - bfh(x3)) << 16);
    const size_t o = (size_t)(n0 + n) * 1024 + k0 + c4;
    *(uint2*)&oh[o] = hv;
    *(uint2*)&ol[o] = lv;
  }
}

// ---------------- split-bf16 MFMA GEMM, 128x128 tile, BK=64 ----------------
// C = A@B, K=1024. MODE 0: A = w (f32, fused split conversion), epilogue QKV scatter.
// MODE 1: A = AVh/AVl (bf16), epilogue += resid -> TMP.
// B given as B^T hi/lo bf16 [N][1024]. LDS XOR-swizzled by (row&7) on 16B chunks.
template<int MODE>
__global__ __launch_bounds__(256) void k_gemm(const float* __restrict__ Af,
                                              const u16* __restrict__ Ahp,
                                              const u16* __restrict__ Alp,
                                              const u16* __restrict__ Bhp,
                                              const u16* __restrict__ Blp,
                                              const float* __restrict__ resid,
                                              float* __restrict__ ws) {
  __shared__ u16 lds[4][128][64];  // 0=Ah 1=Al 2=Bh 3=Bl
  const int tid = threadIdx.x;
  const int wv = tid >> 6, l = tid & 63;
  const int m0 = blockIdx.y << 7, n0 = blockIdx.x << 7;
  const int wr = wv >> 1, wc = wv & 1;

  f32x4 acc[4][4];
#pragma unroll
  for (int i = 0; i < 4; ++i)
#pragma unroll
    for (int j = 0; j < 4; ++j) acc[i][j] = (f32x4){0.f, 0.f, 0.f, 0.f};

  for (int kt = 0; kt < 16; ++kt) {
    const int k0 = kt << 6;
    float4 areg[8];
    if (MODE == 0) {
      const int r_ = tid >> 4, c4 = (tid & 15) << 2;
#pragma unroll
      for (int v = 0; v < 8; ++v)
        areg[v] = *(const float4*)&Af[(size_t)(m0 + (v << 4) + r_) * 1024 + k0 + c4];
    }
    __syncthreads();  // prior compute's LDS reads complete
#pragma unroll
    for (int rnd = 0; rnd < 4; ++rnd) {
      const int rowb = (rnd << 5) + (wv << 3);      // wave-uniform LDS base row
      const int row = rowb + (l >> 3);              // per-lane global row
      const int ko = ((l & 7) ^ (row & 7)) << 3;    // pre-swizzled source chunk
      gld16(Bhp + (size_t)(n0 + row) * 1024 + k0 + ko, &lds[2][rowb][0]);
      gld16(Blp + (size_t)(n0 + row) * 1024 + k0 + ko, &lds[3][rowb][0]);
      if (MODE == 1) {
        gld16(Ahp + (size_t)(m0 + row) * 1024 + k0 + ko, &lds[0][rowb][0]);
        gld16(Alp + (size_t)(m0 + row) * 1024 + k0 + ko, &lds[1][rowb][0]);
      }
    }
    if (MODE == 0) {  // fused f32 -> hi/lo bf16, swizzled ds_write
      const int r_ = tid >> 4, c4 = (tid & 15) << 2;
#pragma unroll
      for (int v = 0; v < 8; ++v) {
        const int row = (v << 4) + r_;
        const float xs[4] = {areg[v].x, areg[v].y, areg[v].z, areg[v].w};
        uint2 hv, lv;
        hv.x = (u32)bft(xs[0]) | ((u32)bft(xs[1]) << 16);
        hv.y = (u32)bft(xs[2]) | ((u32)bft(xs[3]) << 16);
        lv.x = (u32)bft(xs[0] - bfh(xs[0])) | ((u32)bft(xs[1] - bfh(xs[1])) << 16);
        lv.y = (u32)bft(xs[2] - bfh(xs[2])) | ((u32)bft(xs[3] - bfh(xs[3])) << 16);
        const int phys = (((c4 >> 3) ^ (row & 7)) << 3) + (c4 & 7);
        *(uint2*)&lds[0][row][phys] = hv;
        *(uint2*)&lds[1][row][phys] = lv;
      }
    }
    __syncthreads();  // staging visible (vmcnt drained by barrier)
#pragma unroll
    for (int kk = 0; kk < 2; ++kk) {
      short8 fah[4], fal[4], fbh[4], fbl[4];
#pragma unroll
      for (int f = 0; f < 4; ++f) {
        const int ar = (wr << 6) + (f << 4) + (l & 15);
        const int ac = (((kk << 2) + (l >> 4)) ^ (ar & 7)) << 3;
        fah[f] = *(const short8*)&lds[0][ar][ac];
        fal[f] = *(const short8*)&lds[1][ar][ac];
        const int br = (wc << 6) + (f << 4) + (l & 15);
        const int bc = (((kk << 2) + (l >> 4)) ^ (br & 7)) << 3;
        fbh[f] = *(const short8*)&lds[2][br][bc];
        fbl[f] = *(const short8*)&lds[3][br][bc];
      }
#pragma unroll
      for (int fm = 0; fm < 4; ++fm)
#pragma unroll
        for (int fn = 0; fn < 4; ++fn) {
          acc[fm][fn] = __builtin_amdgcn_mfma_f32_16x16x32_bf16(fah[fm], fbh[fn], acc[fm][fn], 0, 0, 0);
          acc[fm][fn] = __builtin_amdgcn_mfma_f32_16x16x32_bf16(fah[fm], fbl[fn], acc[fm][fn], 0, 0, 0);
          acc[fm][fn] = __builtin_amdgcn_mfma_f32_16x16x32_bf16(fal[fm], fbh[fn], acc[fm][fn], 0, 0, 0);
        }
    }
  }

  // epilogue: D row = 4*(lane>>4)+j, col = lane&15  [m89/m91-verified]
#pragma unroll
  for (int fm = 0; fm < 4; ++fm)
#pragma unroll
    for (int fn = 0; fn < 4; ++fn) {
      const int n = n0 + (wc << 6) + (fn << 4) + (l & 15);
#pragma unroll
      for (int j = 0; j < 4; ++j) {
        const int m = m0 + (wr << 6) + (fm << 4) + ((l >> 4) << 2) + j;
        const float v = acc[fm][fn][j];
        if (MODE == 0) {
          const int qq = m >> 3, b = m & 7;
          const int s = n >> 10, hd = (n >> 6) & 15, dh = n & 63;
          const u32 base = (s == 0) ? OFF_Q : (s == 1) ? OFF_K : OFF_V;
          ws[base + (((((b << 4) + hd) << 10) + qq) << 6) + dh] = v;
        } else {
          ws[OFF_TMP + (size_t)m * 1024 + n] = v + resid[(size_t)m * 1024 + n];
        }
      }
    }
}

// ---------------- r @ Wr -> rke (reversed rows), fp32 (small: 2.1 GF) ----------------
__global__ __launch_bounds__(256) void k_proj_r(const float* __restrict__ Rm,
                                                const float* __restrict__ Br,
                                                float* __restrict__ ws) {
  const int bx = blockIdx.x, by = blockIdx.y;
  const int m0 = by * 128, n0 = bx * 128;
  __shared__ float AsT[16][132];
  __shared__ float Bs[16][132];
  const int tid = threadIdx.x;
  const int ty = tid >> 4, tx = tid & 15;
  const int a_row = tid >> 2, a_kc = (tid & 3) << 2;
  const int b_k = tid >> 5, b_col = (tid & 31) << 2;

  float acc[2][2][4][4];
#pragma unroll
  for (int p = 0; p < 2; ++p)
#pragma unroll
    for (int q = 0; q < 2; ++q)
#pragma unroll
      for (int i = 0; i < 4; ++i)
#pragma unroll
        for (int j = 0; j < 4; ++j) acc[p][q][i][j] = 0.f;

  for (int k0 = 0; k0 < 1024; k0 += 16) {
    float4 av0 = *(const float4*)&Rm[(size_t)(m0 + a_row) * 1024 + k0 + a_kc];
    float4 av1 = *(const float4*)&Rm[(size_t)(m0 + a_row + 64) * 1024 + k0 + a_kc];
    float4 bv0 = *(const float4*)&Br[(size_t)(k0 + b_k) * 1024 + n0 + b_col];
    float4 bv1 = *(const float4*)&Br[(size_t)(k0 + b_k + 8) * 1024 + n0 + b_col];
    __syncthreads();
    AsT[a_kc + 0][a_row] = av0.x;  AsT[a_kc + 1][a_row] = av0.y;
    AsT[a_kc + 2][a_row] = av0.z;  AsT[a_kc + 3][a_row] = av0.w;
    AsT[a_kc + 0][a_row + 64] = av1.x;  AsT[a_kc + 1][a_row + 64] = av1.y;
    AsT[a_kc + 2][a_row + 64] = av1.z;  AsT[a_kc + 3][a_row + 64] = av1.w;
    *(float4*)&Bs[b_k][b_col] = bv0;
    *(float4*)&Bs[b_k + 8][b_col] = bv1;
    __syncthreads();
#pragma unroll
    for (int k = 0; k < 16; ++k) {
      float4 a0 = *(const float4*)&AsT[k][ty << 2];
      float4 a1 = *(const float4*)&AsT[k][64 + (ty << 2)];
      float4 b0 = *(const float4*)&Bs[k][tx << 2];
      float4 b1 = *(const float4*)&Bs[k][64 + (tx << 2)];
      float aa[2][4] = {{a0.x, a0.y, a0.z, a0.w}, {a1.x, a1.y, a1.z, a1.w}};
      float bb[2][4] = {{b0.x, b0.y, b0.z, b0.w}, {b1.x, b1.y, b1.z, b1.w}};
#pragma unroll
      for (int p = 0; p < 2; ++p)
#pragma unroll
        for (int q = 0; q < 2; ++q)
#pragma unroll
          for (int i = 0; i < 4; ++i)
#pragma unroll
            for (int j = 0; j < 4; ++j)
              acc[p][q][i][j] += aa[p][i] * bb[q][j];
    }
  }
#pragma unroll
  for (int p = 0; p < 2; ++p)
#pragma unroll
    for (int q = 0; q < 2; ++q) {
      const int cbase = n0 + (q << 6) + (tx << 2);
#pragma unroll
      for (int i = 0; i < 4; ++i) {
        const int m = m0 + (p << 6) + (ty << 2) + i;
        const int nn = (cbase >> 6) & 15, dh = cbase & 63;
        *(float4*)&ws[OFF_RKE + (((nn << 10) + (1023 - m)) << 6) + dh] =
            make_float4(acc[p][q][i][0], acc[p][q][i][1], acc[p][q][i][2], acc[p][q][i][3]);
      }
    }
}

// ---------------- rank-1 bias dot precompute ----------------
__global__ __launch_bounds__(256) void k_bias(const float* __restrict__ rwb,
                                              const float* __restrict__ rrb,
                                              float* __restrict__ ws) {
  const int t = blockIdx.x * 256 + threadIdx.x;
  if (t < 131072) {
    const int j = t & 1023, bn = t >> 10, n = bn & 15;
    const float* kr = ws + OFF_K + ((((size_t)bn << 10) + j) << 6);
    const float* br = rwb + (n << 6);
    float s = 0.f;
#pragma unroll
    for (int d = 0; d < 64; d += 4) {
      float4 kv = *(const float4*)&kr[d];
      float4 bv = *(const float4*)&br[d];
      s += kv.x * bv.x + kv.y * bv.y + kv.z * bv.z + kv.w * bv.w;
    }
    ws[OFF_BK + t] = s;
  } else if (t < 147456) {
    const int u = t - 131072;
    const int d = u & 1023, n = u >> 10;
    const float* rr = ws + OFF_RKE + ((((size_t)n << 10) + d) << 6);
    const float* br = rrb + (n << 6);
    float s = 0.f;
#pragma unroll
    for (int dd = 0; dd < 64; dd += 4) {
      float4 kv = *(const float4*)&rr[dd];
      float4 bv = *(const float4*)&br[dd];
      s += kv.x * bv.x + kv.y * bv.y + kv.z * bv.z + kv.w * bv.w;
    }
    ws[OFF_BRD + n * 1088 + 64 + d] = s;
  } else if (t < 148480) {
    const int u = t - 147456;
    ws[OFF_BRD + (u >> 6) * 1088 + (u & 63)] = 0.f;
  }
}

// ---------------- fused causal flash attention (unchanged core) ----------------
__global__ __launch_bounds__(256) void k_attn(float* __restrict__ ws) {
  __shared__ float qT[64][64];
  __shared__ float pool[12288];

  const int tid = threadIdx.x;
  const int it = blockIdx.x;
  const int bn = blockIdx.y;
  const int b = bn >> 4, n = bn & 15;
  const int i0 = it << 6;
  const float* Q   = ws + OFF_Q   + ((size_t)bn << 16);
  const float* K   = ws + OFF_K   + ((size_t)bn << 16);
  const float* V   = ws + OFF_V   + ((size_t)bn << 16);
  const float* RKE = ws + OFF_RKE + ((size_t)n << 16);
  const float* BKv = ws + OFF_BK  + (bn << 10);
  const float* BRD = ws + OFF_BRD + n * 1088;

  const int rg = tid >> 4, cg = tid & 15;
  const int Dg = rg - cg;

#pragma unroll
  for (int rep = 0; rep < 4; ++rep) {
    const int f = tid + (rep << 8);
    const int row = f >> 4;
    const int dh0 = (f & 15) << 2;
    float4 v = *(const float4*)&Q[((i0 + row) << 6) + dh0];
    const int col = row ^ (((dh0 >> 2) & 7) << 2);
    qT[dh0 + 0][col] = v.x;  qT[dh0 + 1][col] = v.y;
    qT[dh0 + 2][col] = v.z;  qT[dh0 + 3][col] = v.w;
  }

  float O[4][4];
  float m_r[4], l_r[4];
#pragma unroll
  for (int a = 0; a < 4; ++a) {
    m_r[a] = -3.0e38f;
    l_r[a] = 0.f;
#pragma unroll
    for (int d = 0; d < 4; ++d) O[a][d] = 0.f;
  }

  float* kT   = pool;
  float* band = pool + 4096;
  float* Ps   = pool;
  float* Vs   = pool + 4352;

  for (int jt = 0; jt <= it; ++jt) {
    const int j0 = jt << 6;
    const int dbase = i0 - j0;

#pragma unroll
    for (int rep = 0; rep < 4; ++rep) {
      const int f = tid + (rep << 8);
      const int row = f >> 4;
      const int dh0 = (f & 15) << 2;
      float4 v = *(const float4*)&K[((j0 + row) << 6) + dh0];
      const int col = row ^ (((dh0 >> 2) & 7) << 2);
      kT[((dh0 + 0) << 6) + col] = v.x;  kT[((dh0 + 1) << 6) + col] = v.y;
      kT[((dh0 + 2) << 6) + col] = v.z;  kT[((dh0 + 3) << 6) + col] = v.w;
    }
#pragma unroll
    for (int rep = 0; rep < 8; ++rep) {
      const int f = tid + (rep << 8);
      const int bd = f >> 4;
      const int dh0 = (f & 15) << 2;
      const int d = dbase + bd - 63;
      float4 v = make_float4(0.f, 0.f, 0.f, 0.f);
      if (d >= 0 && d < 1024) v = *(const float4*)&RKE[(d << 6) + dh0];
      const int col = bd ^ (((dh0 >> 2) & 7) << 2);
      band[((dh0 + 0) << 7) + col] = v.x;  band[((dh0 + 1) << 7) + col] = v.y;
      band[((dh0 + 2) << 7) + col] = v.z;  band[((dh0 + 3) << 7) + col] = v.w;
    }
    __syncthreads();

    float S[4][4];
#pragma unroll
    for (int a = 0; a < 4; ++a)
#pragma unroll
      for (int c = 0; c < 4; ++c) S[a][c] = 0.f;

#pragma unroll 4
    for (int dh = 0; dh < 64; ++dh) {
      const int sw = (dh >> 2) & 7;
      float4 qv = *(const float4*)&qT[dh][(rg ^ sw) << 2];
      float4 kv = *(const float4*)&kT[(dh << 6) + ((cg ^ sw) << 2)];
      float4 r0 = *(const float4*)&band[(dh << 7) + (((15 + Dg) ^ sw) << 2)];
      float4 r1 = *(const float4*)&band[(dh << 7) + (((16 + Dg) ^ sw) << 2)];
      float qa[4] = {qv.x, qv.y, qv.z, qv.w};
      float kk[4] = {kv.x, kv.y, kv.z, kv.w};
      float rr[8] = {r0.x, r0.y, r0.z, r0.w, r1.x, r1.y, r1.z, r1.w};
#pragma unroll
      for (int a = 0; a < 4; ++a)
#pragma unroll
        for (int c = 0; c < 4; ++c)
          S[a][c] += qa[a] * (kk[c] + rr[3 + a - c]);
    }

    float4 bkv = *(const float4*)&BKv[j0 + (cg << 2)];
    const int dB = 64 + dbase + (Dg << 2);
    float4 q0 = *(const float4*)&BRD[dB - 4];
    float4 q1 = *(const float4*)&BRD[dB];
    float bB[8] = {q0.x, q0.y, q0.z, q0.w, q1.x, q1.y, q1.z, q1.w};
    float bkk[4] = {bkv.x, bkv.y, bkv.z, bkv.w};
#pragma unroll
    for (int a = 0; a < 4; ++a)
#pragma unroll
      for (int c = 0; c < 4; ++c) {
        float s = 0.125f * (S[a][c] + bkk[c] + bB[4 + a - c]);
        if (dbase == 0 && ((rg << 2) + a) < ((cg << 2) + c)) s = -1.0e30f;
        S[a][c] = s;
      }

#pragma unroll
    for (int a = 0; a < 4; ++a) {
      float mt = fmaxf(fmaxf(S[a][0], S[a][1]), fmaxf(S[a][2], S[a][3]));
      mt = fmaxf(mt, __shfl_xor(mt, 1));
      mt = fmaxf(mt, __shfl_xor(mt, 2));
      mt = fmaxf(mt, __shfl_xor(mt, 4));
      mt = fmaxf(mt, __shfl_xor(mt, 8));
      const float mnew = fmaxf(m_r[a], mt);
      const float sc = __expf(m_r[a] - mnew);
      m_r[a] = mnew;
      float rs = 0.f;
#pragma unroll
      for (int c = 0; c < 4; ++c) {
        const float p = __expf(S[a][c] - mnew);
        S[a][c] = p;
        rs += p;
      }
      rs += __shfl_xor(rs, 1);
      rs += __shfl_xor(rs, 2);
      rs += __shfl_xor(rs, 4);
      rs += __shfl_xor(rs, 8);
      l_r[a] = l_r[a] * sc + rs;
#pragma unroll
      for (int d = 0; d < 4; ++d) O[a][d] *= sc;
    }

    __syncthreads();

#pragma unroll
    for (int a = 0; a < 4; ++a)
      *(float4*)&Ps[((rg << 2) + a) * 68 + (cg << 2)] =
          make_float4(S[a][0], S[a][1], S[a][2], S[a][3]);
#pragma unroll
    for (int rep = 0; rep < 4; ++rep) {
      const int f = tid + (rep << 8);
      const int row = f >> 4;
      const int dh0 = (f & 15) << 2;
      *(float4*)&Vs[row * 68 + dh0] = *(const float4*)&V[((j0 + row) << 6) + dh0];
    }
    __syncthreads();

#pragma unroll 2
    for (int tj0 = 0; tj0 < 64; tj0 += 4) {
      float4 p0 = *(const float4*)&Ps[((rg << 2) + 0) * 68 + tj0];
      float4 p1 = *(const float4*)&Ps[((rg << 2) + 1) * 68 + tj0];
      float4 p2 = *(const float4*)&Ps[((rg << 2) + 2) * 68 + tj0];
      float4 p3 = *(const float4*)&Ps[((rg << 2) + 3) * 68 + tj0];
      float4 v0 = *(const float4*)&Vs[(tj0 + 0) * 68 + (cg << 2)];
      float4 v1 = *(const float4*)&Vs[(tj0 + 1) * 68 + (cg << 2)];
      float4 v2 = *(const float4*)&Vs[(tj0 + 2) * 68 + (cg << 2)];
      float4 v3 = *(const float4*)&Vs[(tj0 + 3) * 68 + (cg << 2)];
      float pa[4][4] = {{p0.x, p0.y, p0.z, p0.w}, {p1.x, p1.y, p1.z, p1.w},
                        {p2.x, p2.y, p2.z, p2.w}, {p3.x, p3.y, p3.z, p3.w}};
      float vd[4][4] = {{v0.x, v0.y, v0.z, v0.w}, {v1.x, v1.y, v1.z, v1.w},
                        {v2.x, v2.y, v2.z, v2.w}, {v3.x, v3.y, v3.z, v3.w}};
#pragma unroll
      for (int a = 0; a < 4; ++a)
#pragma unroll
        for (int t = 0; t < 4; ++t)
#pragma unroll
          for (int d = 0; d < 4; ++d) O[a][d] += pa[a][t] * vd[t][d];
    }
    __syncthreads();
  }

  // epilogue: attn_vec -> bf16 hi/lo (consumed by MFMA wo-GEMM)
  u16* const avh = (u16*)ws + UO_AVH;
  u16* const avl = (u16*)ws + UO_AVL;
#pragma unroll
  for (int a = 0; a < 4; ++a) {
    const float inv = 1.f / l_r[a];
    const int i = i0 + (rg << 2) + a;
    const int idx = (((i << 3) + b) << 10) + (n << 6) + (cg << 2);
    float o0 = O[a][0] * inv, o1 = O[a][1] * inv, o2 = O[a][2] * inv, o3 = O[a][3] * inv;
    uint2 hv, lv;
    hv.x = (u32)bft(o0) | ((u32)bft(o1) << 16);
    hv.y = (u32)bft(o2) | ((u32)bft(o3) << 16);
    lv.x = (u32)bft(o0 - bfh(o0)) | ((u32)bft(o1 - bfh(o1)) << 16);
    lv.y = (u32)bft(o2 - bfh(o2)) | ((u32)bft(o3 - bfh(o3)) << 16);
    *(uint2*)&avh[idx] = hv;
    *(uint2*)&avl[idx] = lv;
  }
}

// ---------------- LayerNorm ----------------
__global__ __launch_bounds__(256) void k_ln(const float* __restrict__ x,
                                            const float* __restrict__ g,
                                            const float* __restrict__ bb,
                                            float* __restrict__ out) {
  const int row = blockIdx.x;
  const int tid = threadIdx.x;
  float4 v = *(const float4*)&x[(size_t)row * 1024 + (tid << 2)];
  float s = v.x + v.y + v.z + v.w;
  float q = v.x * v.x + v.y * v.y + v.z * v.z + v.w * v.w;
#pragma unroll
  for (int off = 1; off < 64; off <<= 1) {
    s += __shfl_xor(s, off);
    q += __shfl_xor(q, off);
  }
  __shared__ float ss[4], sq[4];
  if ((tid & 63) == 0) { ss[tid >> 6] = s; sq[tid >> 6] = q; }
  __syncthreads();
  const float S = ss[0] + ss[1] + ss[2] + ss[3];
  const float Q = sq[0] + sq[1] + sq[2] + sq[3];
  const float mu = S * (1.f / 1024.f);
  const float var = Q * (1.f / 1024.f) - mu * mu;
  const float rstd = rsqrtf(var + 1e-5f);
  float4 gv = *(const float4*)&g[tid << 2];
  float4 bv = *(const float4*)&bb[tid << 2];
  float4 o = make_float4((v.x - mu) * rstd * gv.x + bv.x,
                         (v.y - mu) * rstd * gv.y + bv.y,
                         (v.z - mu) * rstd * gv.z + bv.z,
                         (v.w - mu) * rstd * gv.w + bv.w);
  *(float4*)&out[(size_t)row * 1024 + (tid << 2)] = o;
}

// ---------------------------------------------------------------------------
extern "C" void kernel_launch(void* const* d_in, const int* in_sizes, int n_in,
                              void* d_out, int out_size, void* d_ws, size_t ws_size,
                              hipStream_t stream) {
  const float* w    = (const float*)d_in[0];
  const float* r    = (const float*)d_in[1];
  const float* rwb  = (const float*)d_in[2];
  const float* rrb  = (const float*)d_in[3];
  const float* Wqkv = (const float*)d_in[4];
  const float* Wr   = (const float*)d_in[5];
  const float* Wo   = (const float*)d_in[6];
  const float* lng  = (const float*)d_in[7];
  const float* lnb  = (const float*)d_in[8];
  float* out = (float*)d_out;
  float* ws  = (float*)d_ws;
  u16* const wqth = (u16*)ws + UO_WQTH;
  u16* const wqtl = (u16*)ws + UO_WQTL;
  u16* const woth = (u16*)ws + UO_WOTH;
  u16* const wotl = (u16*)ws + UO_WOTL;
  const u16* const avh = (const u16*)ws + UO_AVH;
  const u16* const avl = (const u16*)ws + UO_AVL;

  k_convT<<<768, 256, 0, stream>>>(Wqkv, 3072, wqth, wqtl);
  k_gemm<0><<<dim3(24, 64), 256, 0, stream>>>(w, nullptr, nullptr, wqth, wqtl, nullptr, ws);
  k_proj_r<<<dim3(8, 8), 256, 0, stream>>>(r, Wr, ws);
  k_bias<<<580, 256, 0, stream>>>(rwb, rrb, ws);
  k_attn<<<dim3(16, 128), 256, 0, stream>>>(ws);
  k_convT<<<256, 256, 0, stream>>>(Wo, 1024, woth, wotl);
  k_gemm<1><<<dim3(8, 64), 256, 0, stream>>>(nullptr, avh, avl, woth, wotl, w, ws);
  k_ln<<<8192, 256, 0, stream>>>(ws, lng, lnb, out);
}

// Round 5
// 918.781 us; speedup vs baseline: 1.9200x; 1.4099x over previous
//
#include <hip/hip_runtime.h>

// ---------------------------------------------------------------------------
// RelPartialLearnableMultiHeadAttn (Transformer-XL), MI355X.
// Round 5: attention core moved to f16 MFMA (AC GEMM + Toeplitz-band T GEMM +
// rel-shift gather + PV GEMM). Projection/output GEMMs unchanged (split-bf16).
//
// ws float-offset map (34M floats = 136MB):
//   [0,8M) Q/TMP  [8,16M) K (+WoT after attn)  [16,24M) V  [24,25M) RKE
//   [25M..) BK, BRD   [26,34M) WqkvT (phase0-1) / AVh,AVl (phase3+)
// ---------------------------------------------------------------------------

typedef __attribute__((ext_vector_type(8))) short short8;
typedef __attribute__((ext_vector_type(4))) float f32x4;
typedef _Float16 f16;
typedef __attribute__((ext_vector_type(8))) _Float16 f16x8;
typedef unsigned short u16;
typedef unsigned int u32;

#define OFF_Q   0u
#define OFF_K   (8u<<20)
#define OFF_V   (16u<<20)
#define OFF_RKE (24u<<20)
#define OFF_BK  (25u<<20)
#define OFF_BRD ((25u<<20) + (1u<<17))
#define OFF_TMP 0u
// ushort offsets into ws:
#define UO_WQTH (52u<<20)
#define UO_WQTL (55u<<20)
#define UO_AVH  (52u<<20)
#define UO_AVL  (60u<<20)
#define UO_WOTH (16u<<20)
#define UO_WOTL (17u<<20)

__device__ __forceinline__ u16 bft(float x) { return (u16)(__float_as_uint(x) >> 16); }
__device__ __forceinline__ float bfh(float x) { return __uint_as_float(__float_as_uint(x) & 0xFFFF0000u); }
__device__ __forceinline__ u16 f16b(float x) { f16 h = (f16)x; u16 r; __builtin_memcpy(&r, &h, 2); return r; }
__device__ __forceinline__ float f16f(u16 v) { f16 h; __builtin_memcpy(&h, &v, 2); return (float)h; }
__device__ __forceinline__ u32 pk2(float a, float b) { return (u32)f16b(a) | ((u32)f16b(b) << 16); }

__device__ __forceinline__ void gld16(const void* g, void* s) {
  __builtin_amdgcn_global_load_lds((const __attribute__((address_space(1))) u32*)g,
                                   (__attribute__((address_space(3))) u32*)s, 16, 0, 0);
}

// ---------------- transpose + split-bf16 weight conversion ----------------
__global__ __launch_bounds__(256) void k_convT(const float* __restrict__ src, int ldN,
                                               u16* __restrict__ oh, u16* __restrict__ ol) {
  __shared__ float t[64][65];
  const int bt = blockIdx.x, kt = bt & 15, nt = bt >> 4;
  const int k0 = kt << 6, n0 = nt << 6, tid = threadIdx.x;
  const int r = tid >> 4, c4 = (tid & 15) << 2;
#pragma unroll
  for (int rep = 0; rep < 4; ++rep) {
    const int row = (rep << 4) + r;
    float4 v = *(const float4*)&src[(size_t)(k0 + row) * ldN + n0 + c4];
    t[c4 + 0][row] = v.x; t[c4 + 1][row] = v.y;
    t[c4 + 2][row] = v.z; t[c4 + 3][row] = v.w;
  }
  __syncthreads();
#pragma unroll
  for (int rep = 0; rep < 4; ++rep) {
    const int n = (rep << 4) + r;
    float x0 = t[n][c4 + 0], x1 = t[n][c4 + 1], x2 = t[n][c4 + 2], x3 = t[n][c4 + 3];
    uint2 hv, lv;
    hv.x = (u32)bft(x0) | ((u32)bft(x1) << 16);
    hv.y = (u32)bft(x2) | ((u32)bft(x3) << 16);
    lv.x = (u32)bft(x0 - bfh(x0)) | ((u32)bft(x1 - bfh(x1)) << 16);
    lv.y = (u32)bft(x2 - bfh(x2)) | ((u32)bft(x3 - bfh(x3)) << 16);
    const size_t o = (size_t)(n0 + n) * 1024 + k0 + c4;
    *(uint2*)&oh[o] = hv;
    *(uint2*)&ol[o] = lv;
  }
}

// ---------------- split-bf16 MFMA GEMM, 128x128 tile, BK=64 ----------------
template<int MODE>
__global__ __launch_bounds__(256) void k_gemm(const float* __restrict__ Af,
                                              const u16* __restrict__ Ahp,
                                              const u16* __restrict__ Alp,
                                              const u16* __restrict__ Bhp,
                                              const u16* __restrict__ Blp,
                                              const float* __restrict__ resid,
                                              float* __restrict__ ws) {
  __shared__ u16 lds[4][128][64];
  const int tid = threadIdx.x;
  const int wv = tid >> 6, l = tid & 63;
  const int m0 = blockIdx.y << 7, n0 = blockIdx.x << 7;
  const int wr = wv >> 1, wc = wv & 1;

  f32x4 acc[4][4];
#pragma unroll
  for (int i = 0; i < 4; ++i)
#pragma unroll
    for (int j = 0; j < 4; ++j) acc[i][j] = (f32x4){0.f, 0.f, 0.f, 0.f};

  for (int kt = 0; kt < 16; ++kt) {
    const int k0 = kt << 6;
    float4 areg[8];
    if (MODE == 0) {
      const int r_ = tid >> 4, c4 = (tid & 15) << 2;
#pragma unroll
      for (int v = 0; v < 8; ++v)
        areg[v] = *(const float4*)&Af[(size_t)(m0 + (v << 4) + r_) * 1024 + k0 + c4];
    }
    __syncthreads();
#pragma unroll
    for (int rnd = 0; rnd < 4; ++rnd) {
      const int rowb = (rnd << 5) + (wv << 3);
      const int row = rowb + (l >> 3);
      const int ko = ((l & 7) ^ (row & 7)) << 3;
      gld16(Bhp + (size_t)(n0 + row) * 1024 + k0 + ko, &lds[2][rowb][0]);
      gld16(Blp + (size_t)(n0 + row) * 1024 + k0 + ko, &lds[3][rowb][0]);
      if (MODE == 1) {
        gld16(Ahp + (size_t)(m0 + row) * 1024 + k0 + ko, &lds[0][rowb][0]);
        gld16(Alp + (size_t)(m0 + row) * 1024 + k0 + ko, &lds[1][rowb][0]);
      }
    }
    if (MODE == 0) {
      const int r_ = tid >> 4, c4 = (tid & 15) << 2;
#pragma unroll
      for (int v = 0; v < 8; ++v) {
        const int row = (v << 4) + r_;
        const float xs[4] = {areg[v].x, areg[v].y, areg[v].z, areg[v].w};
        uint2 hv, lv;
        hv.x = (u32)bft(xs[0]) | ((u32)bft(xs[1]) << 16);
        hv.y = (u32)bft(xs[2]) | ((u32)bft(xs[3]) << 16);
        lv.x = (u32)bft(xs[0] - bfh(xs[0])) | ((u32)bft(xs[1] - bfh(xs[1])) << 16);
        lv.y = (u32)bft(xs[2] - bfh(xs[2])) | ((u32)bft(xs[3] - bfh(xs[3])) << 16);
        const int phys = (((c4 >> 3) ^ (row & 7)) << 3) + (c4 & 7);
        *(uint2*)&lds[0][row][phys] = hv;
        *(uint2*)&lds[1][row][phys] = lv;
      }
    }
    __syncthreads();
#pragma unroll
    for (int kk = 0; kk < 2; ++kk) {
      short8 fah[4], fal[4], fbh[4], fbl[4];
#pragma unroll
      for (int f = 0; f < 4; ++f) {
        const int ar = (wr << 6) + (f << 4) + (l & 15);
        const int ac = (((kk << 2) + (l >> 4)) ^ (ar & 7)) << 3;
        fah[f] = *(const short8*)&lds[0][ar][ac];
        fal[f] = *(const short8*)&lds[1][ar][ac];
        const int br = (wc << 6) + (f << 4) + (l & 15);
        const int bc = (((kk << 2) + (l >> 4)) ^ (br & 7)) << 3;
        fbh[f] = *(const short8*)&lds[2][br][bc];
        fbl[f] = *(const short8*)&lds[3][br][bc];
      }
#pragma unroll
      for (int fm = 0; fm < 4; ++fm)
#pragma unroll
        for (int fn = 0; fn < 4; ++fn) {
          acc[fm][fn] = __builtin_amdgcn_mfma_f32_16x16x32_bf16(fah[fm], fbh[fn], acc[fm][fn], 0, 0, 0);
          acc[fm][fn] = __builtin_amdgcn_mfma_f32_16x16x32_bf16(fah[fm], fbl[fn], acc[fm][fn], 0, 0, 0);
          acc[fm][fn] = __builtin_amdgcn_mfma_f32_16x16x32_bf16(fal[fm], fbh[fn], acc[fm][fn], 0, 0, 0);
        }
    }
  }

#pragma unroll
  for (int fm = 0; fm < 4; ++fm)
#pragma unroll
    for (int fn = 0; fn < 4; ++fn) {
      const int n = n0 + (wc << 6) + (fn << 4) + (l & 15);
#pragma unroll
      for (int j = 0; j < 4; ++j) {
        const int m = m0 + (wr << 6) + (fm << 4) + ((l >> 4) << 2) + j;
        const float v = acc[fm][fn][j];
        if (MODE == 0) {
          const int qq = m >> 3, b = m & 7;
          const int s = n >> 10, hd = (n >> 6) & 15, dh = n & 63;
          const u32 base = (s == 0) ? OFF_Q : (s == 1) ? OFF_K : OFF_V;
          ws[base + (((((b << 4) + hd) << 10) + qq) << 6) + dh] = v;
        } else {
          ws[OFF_TMP + (size_t)m * 1024 + n] = v + resid[(size_t)m * 1024 + n];
        }
      }
    }
}

// ---------------- r @ Wr -> rke (reversed rows), fp32 ----------------
__global__ __launch_bounds__(256) void k_proj_r(const float* __restrict__ Rm,
                                                const float* __restrict__ Br,
                                                float* __restrict__ ws) {
  const int bx = blockIdx.x, by = blockIdx.y;
  const int m0 = by * 128, n0 = bx * 128;
  __shared__ float AsT[16][132];
  __shared__ float Bs[16][132];
  const int tid = threadIdx.x;
  const int ty = tid >> 4, tx = tid & 15;
  const int a_row = tid >> 2, a_kc = (tid & 3) << 2;
  const int b_k = tid >> 5, b_col = (tid & 31) << 2;

  float acc[2][2][4][4];
#pragma unroll
  for (int p = 0; p < 2; ++p)
#pragma unroll
    for (int q = 0; q < 2; ++q)
#pragma unroll
      for (int i = 0; i < 4; ++i)
#pragma unroll
        for (int j = 0; j < 4; ++j) acc[p][q][i][j] = 0.f;

  for (int k0 = 0; k0 < 1024; k0 += 16) {
    float4 av0 = *(const float4*)&Rm[(size_t)(m0 + a_row) * 1024 + k0 + a_kc];
    float4 av1 = *(const float4*)&Rm[(size_t)(m0 + a_row + 64) * 1024 + k0 + a_kc];
    float4 bv0 = *(const float4*)&Br[(size_t)(k0 + b_k) * 1024 + n0 + b_col];
    float4 bv1 = *(const float4*)&Br[(size_t)(k0 + b_k + 8) * 1024 + n0 + b_col];
    __syncthreads();
    AsT[a_kc + 0][a_row] = av0.x;  AsT[a_kc + 1][a_row] = av0.y;
    AsT[a_kc + 2][a_row] = av0.z;  AsT[a_kc + 3][a_row] = av0.w;
    AsT[a_kc + 0][a_row + 64] = av1.x;  AsT[a_kc + 1][a_row + 64] = av1.y;
    AsT[a_kc + 2][a_row + 64] = av1.z;  AsT[a_kc + 3][a_row + 64] = av1.w;
    *(float4*)&Bs[b_k][b_col] = bv0;
    *(float4*)&Bs[b_k + 8][b_col] = bv1;
    __syncthreads();
#pragma unroll
    for (int k = 0; k < 16; ++k) {
      float4 a0 = *(const float4*)&AsT[k][ty << 2];
      float4 a1 = *(const float4*)&AsT[k][64 + (ty << 2)];
      float4 b0 = *(const float4*)&Bs[k][tx << 2];
      float4 b1 = *(const float4*)&Bs[k][64 + (tx << 2)];
      float aa[2][4] = {{a0.x, a0.y, a0.z, a0.w}, {a1.x, a1.y, a1.z, a1.w}};
      float bb[2][4] = {{b0.x, b0.y, b0.z, b0.w}, {b1.x, b1.y, b1.z, b1.w}};
#pragma unroll
      for (int p = 0; p < 2; ++p)
#pragma unroll
        for (int q = 0; q < 2; ++q)
#pragma unroll
          for (int i = 0; i < 4; ++i)
#pragma unroll
            for (int j = 0; j < 4; ++j)
              acc[p][q][i][j] += aa[p][i] * bb[q][j];
    }
  }
#pragma unroll
  for (int p = 0; p < 2; ++p)
#pragma unroll
    for (int q = 0; q < 2; ++q) {
      const int cbase = n0 + (q << 6) + (tx << 2);
#pragma unroll
      for (int i = 0; i < 4; ++i) {
        const int m = m0 + (p << 6) + (ty << 2) + i;
        const int nn = (cbase >> 6) & 15, dh = cbase & 63;
        *(float4*)&ws[OFF_RKE + (((nn << 10) + (1023 - m)) << 6) + dh] =
            make_float4(acc[p][q][i][0], acc[p][q][i][1], acc[p][q][i][2], acc[p][q][i][3]);
      }
    }
}

// ---------------- rank-1 bias dot precompute ----------------
__global__ __launch_bounds__(256) void k_bias(const float* __restrict__ rwb,
                                              const float* __restrict__ rrb,
                                              float* __restrict__ ws) {
  const int t = blockIdx.x * 256 + threadIdx.x;
  if (t < 131072) {
    const int j = t & 1023, bn = t >> 10, n = bn & 15;
    const float* kr = ws + OFF_K + ((((size_t)bn << 10) + j) << 6);
    const float* br = rwb + (n << 6);
    float s = 0.f;
#pragma unroll
    for (int d = 0; d < 64; d += 4) {
      float4 kv = *(const float4*)&kr[d];
      float4 bv = *(const float4*)&br[d];
      s += kv.x * bv.x + kv.y * bv.y + kv.z * bv.z + kv.w * bv.w;
    }
    ws[OFF_BK + t] = s;
  } else if (t < 147456) {
    const int u = t - 131072;
    const int d = u & 1023, n = u >> 10;
    const float* rr = ws + OFF_RKE + ((((size_t)n << 10) + d) << 6);
    const float* br = rrb + (n << 6);
    float s = 0.f;
#pragma unroll
    for (int dd = 0; dd < 64; dd += 4) {
      float4 kv = *(const float4*)&rr[dd];
      float4 bv = *(const float4*)&br[dd];
      s += kv.x * bv.x + kv.y * bv.y + kv.z * bv.z + kv.w * bv.w;
    }
    ws[OFF_BRD + n * 1088 + 64 + d] = s;
  } else if (t < 148480) {
    const int u = t - 147456;
    ws[OFF_BRD + (u >> 6) * 1088 + (u & 63)] = 0.f;
  }
}

// ---------------- f16 MFMA flash attention with Toeplitz rel-band ----------------
// Per tile: AC = Q@K^T (GEMM), T = Q@band^T (GEMM, brd folded in at T-write),
// rel-shift = wave-local LDS gather BD[i,j] = T[i, ri-cj+63], PV = P@V (GEMM).
// All MFMA-path LDS tiles [rows][64] f16 with 16B-chunk XOR swizzle (row&7).
__global__ __launch_bounds__(256) void k_attn(float* __restrict__ ws) {
  __shared__ __align__(16) u16 Qf[4096];     // [64][64]
  __shared__ __align__(16) u16 pool[12288];  // ph1: Kf[0:4096]=[64][64], band[4096:12288]=[128][64]
                                             // ph2: Tf[0:8192]=[64][128] (unswz), Vt[8192:12288]=[64][64]
  __shared__ __align__(16) u16 Pf[4096];     // [64][64]

  const int tid = threadIdx.x, wv = tid >> 6, l = tid & 63;
  const int it = blockIdx.x, bn = blockIdx.y, b = bn >> 4, n = bn & 15;
  const int i0 = it << 6;
  const float* Q   = ws + OFF_Q   + ((size_t)bn << 16);
  const float* K   = ws + OFF_K   + ((size_t)bn << 16);
  const float* V   = ws + OFF_V   + ((size_t)bn << 16);
  const float* RKE = ws + OFF_RKE + ((size_t)n << 16);
  const float* BKp = ws + OFF_BK  + (bn << 10);
  const float* BRD = ws + OFF_BRD + n * 1088;

  const int r_ = tid >> 4, c4 = (tid & 15) << 2;
  const int lg = l >> 4, lc = l & 15;          // lane k-group / lane col
  const int rown = (wv << 4) + (lg << 2);      // D-layout row base (tile-local)

  // stage Q once (f16, swizzled)
#pragma unroll
  for (int v = 0; v < 4; ++v) {
    const int row = (v << 4) + r_;
    float4 q = *(const float4*)&Q[((i0 + row) << 6) + c4];
    const int idx = (row << 6) + (((c4 >> 3) ^ (row & 7)) << 3) + (c4 & 7);
    *(uint2*)&Qf[idx] = make_uint2(pk2(q.x, q.y), pk2(q.z, q.w));
  }

  f32x4 oacc[4];
  float m_r[4], l_r[4];
#pragma unroll
  for (int j = 0; j < 4; ++j) {
    m_r[j] = -3.0e38f; l_r[j] = 0.f;
    oacc[j] = (f32x4){0.f, 0.f, 0.f, 0.f};
  }

  for (int jt = 0; jt <= it; ++jt) {
    const int j0 = jt << 6, dbase = i0 - j0;

    // issue K/V global loads early (overlap prev PV + barrier)
    float4 kv[4], vv[4];
#pragma unroll
    for (int v = 0; v < 4; ++v) {
      const int row = (v << 4) + r_;
      kv[v] = *(const float4*)&K[((j0 + row) << 6) + c4];
      vv[v] = *(const float4*)&V[((j0 + row) << 6) + c4];
    }
    __syncthreads();  // sync0: pool free (prev tile's mfma reads done)

    // stage K + band (f16, swizzled)
#pragma unroll
    for (int v = 0; v < 4; ++v) {
      const int row = (v << 4) + r_;
      const int idx = (row << 6) + (((c4 >> 3) ^ (row & 7)) << 3) + (c4 & 7);
      *(uint2*)&pool[idx] = make_uint2(pk2(kv[v].x, kv[v].y), pk2(kv[v].z, kv[v].w));
    }
#pragma unroll
    for (int v = 0; v < 8; ++v) {
      const int bd = (v << 4) + r_;
      const int d = dbase + bd - 63;
      float4 bvv = make_float4(0.f, 0.f, 0.f, 0.f);
      if (d >= 0 && d < 1024) bvv = *(const float4*)&RKE[(d << 6) + c4];
      const int idx = 4096 + (bd << 6) + (((c4 >> 3) ^ (bd & 7)) << 3) + (c4 & 7);
      *(uint2*)&pool[idx] = make_uint2(pk2(bvv.x, bvv.y), pk2(bvv.z, bvv.w));
    }
    __syncthreads();  // sync1: staging visible

    // AC + T MFMA (wave owns rows [16wv,16wv+16))
    f32x4 sacc[4], tacc[8];
#pragma unroll
    for (int f = 0; f < 4; ++f) sacc[f] = (f32x4){0.f, 0.f, 0.f, 0.f};
#pragma unroll
    for (int f = 0; f < 8; ++f) tacc[f] = (f32x4){0.f, 0.f, 0.f, 0.f};
    const int ar = (wv << 4) + lc;
#pragma unroll
    for (int kk = 0; kk < 2; ++kk) {
      const int ch = (kk << 2) + lg;
      f16x8 af = *(const f16x8*)&Qf[(ar << 6) + ((ch ^ (ar & 7)) << 3)];
#pragma unroll
      for (int fc = 0; fc < 4; ++fc) {
        const int br = (fc << 4) + lc;
        f16x8 bf = *(const f16x8*)&pool[(br << 6) + ((ch ^ (br & 7)) << 3)];
        sacc[fc] = __builtin_amdgcn_mfma_f32_16x16x32_f16(af, bf, sacc[fc], 0, 0, 0);
      }
#pragma unroll
      for (int fc = 0; fc < 8; ++fc) {
        const int br = (fc << 4) + lc;
        f16x8 bf = *(const f16x8*)&pool[4096 + (br << 6) + ((ch ^ (br & 7)) << 3)];
        tacc[fc] = __builtin_amdgcn_mfma_f32_16x16x32_f16(af, bf, tacc[fc], 0, 0, 0);
      }
    }
    __syncthreads();  // sync2: K/band reads done, pool reusable

    // write T (+brd) [wave-local rows]; stage V^T (cross-wave)
#pragma unroll
    for (int fc = 0; fc < 8; ++fc) {
      const int col = (fc << 4) + lc;
      const float brd_v = (dbase + col - 63 < 1024) ? BRD[1 + dbase + col] : 0.f;
#pragma unroll
      for (int j = 0; j < 4; ++j)
        pool[((rown + j) << 7) + col] = f16b(tacc[fc][j] + brd_v);
    }
#pragma unroll
    for (int v = 0; v < 4; ++v) {
      const int row = (v << 4) + r_;
      const float x[4] = {vv[v].x, vv[v].y, vv[v].z, vv[v].w};
#pragma unroll
      for (int e = 0; e < 4; ++e) {
        const int dh = c4 + e;
        pool[8192 + (dh << 6) + (((row >> 3) ^ (dh & 7)) << 3) + (row & 7)] = f16b(x[e]);
      }
    }
    // no barrier: T gather below is wave-local (compiler orders via lgkmcnt)

    // gather + biases + mask -> S; online softmax; write P (wave-local rows)
    float S[4][4];
#pragma unroll
    for (int fc = 0; fc < 4; ++fc) {
      const int cj = (fc << 4) + lc;
      const float bkv = BKp[j0 + cj];
#pragma unroll
      for (int j = 0; j < 4; ++j) {
        const int ri = rown + j;
        const float t = f16f(pool[(ri << 7) + (ri - cj + 63)]);
        float s = 0.125f * (sacc[fc][j] + bkv + t);
        if (dbase == 0 && ri < cj) s = -1.0e30f;
        S[fc][j] = s;
      }
    }
#pragma unroll
    for (int j = 0; j < 4; ++j) {
      float mt = fmaxf(fmaxf(S[0][j], S[1][j]), fmaxf(S[2][j], S[3][j]));
      mt = fmaxf(mt, __shfl_xor(mt, 1));
      mt = fmaxf(mt, __shfl_xor(mt, 2));
      mt = fmaxf(mt, __shfl_xor(mt, 4));
      mt = fmaxf(mt, __shfl_xor(mt, 8));
      const float mnew = fmaxf(m_r[j], mt);
      const float sc = __expf(m_r[j] - mnew);
      m_r[j] = mnew;
      const int r = rown + j;
      float rs = 0.f;
#pragma unroll
      for (int fc = 0; fc < 4; ++fc) {
        const float p = __expf(S[fc][j] - mnew);
        rs += p;
        const int cj = (fc << 4) + lc;
        Pf[(r << 6) + (((cj >> 3) ^ (r & 7)) << 3) + (cj & 7)] = f16b(p);
      }
      rs += __shfl_xor(rs, 1);
      rs += __shfl_xor(rs, 2);
      rs += __shfl_xor(rs, 4);
      rs += __shfl_xor(rs, 8);
      l_r[j] = l_r[j] * sc + rs;
#pragma unroll
      for (int fc = 0; fc < 4; ++fc) oacc[fc] *= sc;
    }
    __syncthreads();  // sync4: V^T staged (cross-wave)

    // PV MFMA
    const int pr = (wv << 4) + lc;
#pragma unroll
    for (int kk = 0; kk < 2; ++kk) {
      const int ch = (kk << 2) + lg;
      f16x8 pa = *(const f16x8*)&Pf[(pr << 6) + ((ch ^ (pr & 7)) << 3)];
#pragma unroll
      for (int fc = 0; fc < 4; ++fc) {
        const int vr = (fc << 4) + lc;
        f16x8 vb = *(const f16x8*)&pool[8192 + (vr << 6) + ((ch ^ (vr & 7)) << 3)];
        oacc[fc] = __builtin_amdgcn_mfma_f32_16x16x32_f16(pa, vb, oacc[fc], 0, 0, 0);
      }
    }
  }

  // epilogue: normalize, write attn_vec as bf16 hi/lo
  u16* const avh = (u16*)ws + UO_AVH;
  u16* const avl = (u16*)ws + UO_AVL;
#pragma unroll
  for (int j = 0; j < 4; ++j) {
    const float inv = 1.f / l_r[j];
    const int i = i0 + rown + j;
#pragma unroll
    for (int fc = 0; fc < 4; ++fc) {
      const int dh = (fc << 4) + lc;
      const float val = oacc[fc][j] * inv;
      const size_t idx = (((size_t)(i << 3) + b) << 10) + (n << 6) + dh;
      avh[idx] = bft(val);
      avl[idx] = bft(val - bfh(val));
    }
  }
}

// ---------------- LayerNorm ----------------
__global__ __launch_bounds__(256) void k_ln(const float* __restrict__ x,
                                            const float* __restrict__ g,
                                            const float* __restrict__ bb,
                                            float* __restrict__ out) {
  const int row = blockIdx.x;
  const int tid = threadIdx.x;
  float4 v = *(const float4*)&x[(size_t)row * 1024 + (tid << 2)];
  float s = v.x + v.y + v.z + v.w;
  float q = v.x * v.x + v.y * v.y + v.z * v.z + v.w * v.w;
#pragma unroll
  for (int off = 1; off < 64; off <<= 1) {
    s += __shfl_xor(s, off);
    q += __shfl_xor(q, off);
  }
  __shared__ float ss[4], sq[4];
  if ((tid & 63) == 0) { ss[tid >> 6] = s; sq[tid >> 6] = q; }
  __syncthreads();
  const float S = ss[0] + ss[1] + ss[2] + ss[3];
  const float Q = sq[0] + sq[1] + sq[2] + sq[3];
  const float mu = S * (1.f / 1024.f);
  const float var = Q * (1.f / 1024.f) - mu * mu;
  const float rstd = rsqrtf(var + 1e-5f);
  float4 gv = *(const float4*)&g[tid << 2];
  float4 bv = *(const float4*)&bb[tid << 2];
  float4 o = make_float4((v.x - mu) * rstd * gv.x + bv.x,
                         (v.y - mu) * rstd * gv.y + bv.y,
                         (v.z - mu) * rstd * gv.z + bv.z,
                         (v.w - mu) * rstd * gv.w + bv.w);
  *(float4*)&out[(size_t)row * 1024 + (tid << 2)] = o;
}

// ---------------------------------------------------------------------------
extern "C" void kernel_launch(void* const* d_in, const int* in_sizes, int n_in,
                              void* d_out, int out_size, void* d_ws, size_t ws_size,
                              hipStream_t stream) {
  const float* w    = (const float*)d_in[0];
  const float* r    = (const float*)d_in[1];
  const float* rwb  = (const float*)d_in[2];
  const float* rrb  = (const float*)d_in[3];
  const float* Wqkv = (const float*)d_in[4];
  const float* Wr   = (const float*)d_in[5];
  const float* Wo   = (const float*)d_in[6];
  const float* lng  = (const float*)d_in[7];
  const float* lnb  = (const float*)d_in[8];
  float* out = (float*)d_out;
  float* ws  = (float*)d_ws;
  u16* const wqth = (u16*)ws + UO_WQTH;
  u16* const wqtl = (u16*)ws + UO_WQTL;
  u16* const woth = (u16*)ws + UO_WOTH;
  u16* const wotl = (u16*)ws + UO_WOTL;
  const u16* const avh = (const u16*)ws + UO_AVH;
  const u16* const avl = (const u16*)ws + UO_AVL;

  k_convT<<<768, 256, 0, stream>>>(Wqkv, 3072, wqth, wqtl);
  k_gemm<0><<<dim3(24, 64), 256, 0, stream>>>(w, nullptr, nullptr, wqth, wqtl, nullptr, ws);
  k_proj_r<<<dim3(8, 8), 256, 0, stream>>>(r, Wr, ws);
  k_bias<<<580, 256, 0, stream>>>(rwb, rrb, ws);
  k_attn<<<dim3(16, 128), 256, 0, stream>>>(ws);
  k_convT<<<256, 256, 0, stream>>>(Wo, 1024, woth, wotl);
  k_gemm<1><<<dim3(8, 64), 256, 0, stream>>>(nullptr, avh, avl, woth, wotl, w, ws);
  k_ln<<<8192, 256, 0, stream>>>(ws, lng, lnb, out);
}

// Round 7
// 623.408 us; speedup vs baseline: 2.8297x; 1.4738x over previous
//
#include <hip/hip_runtime.h>

// ---------------------------------------------------------------------------
// RelPartialLearnableMultiHeadAttn (Transformer-XL), MI355X.
// Round 7 (= audited round-6 resubmit): attention hot loop = pure
// {global_load_lds staging + f16 MFMA + softmax}. All f32->f16 conversion
// hoisted to producer kernels (pre-swizzled f16 Q/K/V/RKE + V^T). Rescale bug
// fixed (per-row). Heavy-first dispatch.
//
// ws map: f32 [0,8M) TMP (k_gemm<1> out; QF16 dead by then)
//   u16: QF[0,8.4M) KF[16M,24.4M) VF[32M,40.4M) VT[40M..48.4M) RKEF[48M,49.2M)
//   f32: BK 25M.. BRD 25M+128K..   f32 [26,34M): WqkvT (early) / AVh,AVl (late)
//   WoT u16 at 16M/17M (KF16 region, dead after attn)
// ---------------------------------------------------------------------------

typedef __attribute__((ext_vector_type(8))) short short8;
typedef __attribute__((ext_vector_type(4))) float f32x4;
typedef _Float16 f16;
typedef __attribute__((ext_vector_type(8))) _Float16 f16x8;
typedef unsigned short u16;
typedef unsigned int u32;

#define OFF_BK  (25u<<20)
#define OFF_BRD ((25u<<20) + (1u<<17))
#define OFF_TMP 0u
// u16 offsets
#define UO_QF   0u
#define UO_KF   (16u<<20)
#define UO_VF   (32u<<20)
#define UO_VT   (40u<<20)
#define UO_RKEF (48u<<20)
#define UO_WQTH (52u<<20)
#define UO_WQTL (55u<<20)
#define UO_AVH  (52u<<20)
#define UO_AVL  (60u<<20)
#define UO_WOTH (16u<<20)
#define UO_WOTL (17u<<20)

__device__ __forceinline__ u16 bft(float x) { return (u16)(__float_as_uint(x) >> 16); }
__device__ __forceinline__ float bfh(float x) { return __uint_as_float(__float_as_uint(x) & 0xFFFF0000u); }
__device__ __forceinline__ u16 f16b(float x) { f16 h = (f16)x; u16 r; __builtin_memcpy(&r, &h, 2); return r; }
__device__ __forceinline__ float f16f(u16 v) { f16 h; __builtin_memcpy(&h, &v, 2); return (float)h; }

__device__ __forceinline__ void gld16(const void* g, void* s) {
  __builtin_amdgcn_global_load_lds((const __attribute__((address_space(1))) u32*)g,
                                   (__attribute__((address_space(3))) u32*)s, 16, 0, 0);
}
// swizzled f16 element offset within a 64-elem row, key (row&7)
__device__ __forceinline__ int swz(int row, int c) {
  return (((c >> 3) ^ (row & 7)) << 3) + (c & 7);
}

// ---------------- transpose + split-bf16 weight conversion ----------------
__global__ __launch_bounds__(256) void k_convT(const float* __restrict__ src, int ldN,
                                               u16* __restrict__ oh, u16* __restrict__ ol) {
  __shared__ float t[64][65];
  const int bt = blockIdx.x, kt = bt & 15, nt = bt >> 4;
  const int k0 = kt << 6, n0 = nt << 6, tid = threadIdx.x;
  const int r = tid >> 4, c4 = (tid & 15) << 2;
#pragma unroll
  for (int rep = 0; rep < 4; ++rep) {
    const int row = (rep << 4) + r;
    float4 v = *(const float4*)&src[(size_t)(k0 + row) * ldN + n0 + c4];
    t[c4 + 0][row] = v.x; t[c4 + 1][row] = v.y;
    t[c4 + 2][row] = v.z; t[c4 + 3][row] = v.w;
  }
  __syncthreads();
#pragma unroll
  for (int rep = 0; rep < 4; ++rep) {
    const int n = (rep << 4) + r;
    float x0 = t[n][c4 + 0], x1 = t[n][c4 + 1], x2 = t[n][c4 + 2], x3 = t[n][c4 + 3];
    uint2 hv, lv;
    hv.x = (u32)bft(x0) | ((u32)bft(x1) << 16);
    hv.y = (u32)bft(x2) | ((u32)bft(x3) << 16);
    lv.x = (u32)bft(x0 - bfh(x0)) | ((u32)bft(x1 - bfh(x1)) << 16);
    lv.y = (u32)bft(x2 - bfh(x2)) | ((u32)bft(x3 - bfh(x3)) << 16);
    const size_t o = (size_t)(n0 + n) * 1024 + k0 + c4;
    *(uint2*)&oh[o] = hv;
    *(uint2*)&ol[o] = lv;
  }
}

// ---------------- split-bf16 MFMA GEMM, 128x128 tile, BK=64 ----------------
// MODE 0: A=w f32 (fused split), epilogue -> QF16/KF16/VF16 (f16, pre-swizzled)
// MODE 1: A=AVh/AVl bf16, epilogue += resid -> TMP f32
template<int MODE>
__global__ __launch_bounds__(256) void k_gemm(const float* __restrict__ Af,
                                              const u16* __restrict__ Ahp,
                                              const u16* __restrict__ Alp,
                                              const u16* __restrict__ Bhp,
                                              const u16* __restrict__ Blp,
                                              const float* __restrict__ resid,
                                              float* __restrict__ ws) {
  __shared__ u16 lds[4][128][64];
  const int tid = threadIdx.x;
  const int wv = tid >> 6, l = tid & 63;
  const int m0 = blockIdx.y << 7, n0 = blockIdx.x << 7;
  const int wr = wv >> 1, wc = wv & 1;

  f32x4 acc[4][4];
#pragma unroll
  for (int i = 0; i < 4; ++i)
#pragma unroll
    for (int j = 0; j < 4; ++j) acc[i][j] = (f32x4){0.f, 0.f, 0.f, 0.f};

  for (int kt = 0; kt < 16; ++kt) {
    const int k0 = kt << 6;
    float4 areg[8];
    if (MODE == 0) {
      const int r_ = tid >> 4, c4 = (tid & 15) << 2;
#pragma unroll
      for (int v = 0; v < 8; ++v)
        areg[v] = *(const float4*)&Af[(size_t)(m0 + (v << 4) + r_) * 1024 + k0 + c4];
    }
    __syncthreads();
#pragma unroll
    for (int rnd = 0; rnd < 4; ++rnd) {
      const int rowb = (rnd << 5) + (wv << 3);
      const int row = rowb + (l >> 3);
      const int ko = ((l & 7) ^ (row & 7)) << 3;
      gld16(Bhp + (size_t)(n0 + row) * 1024 + k0 + ko, &lds[2][rowb][0]);
      gld16(Blp + (size_t)(n0 + row) * 1024 + k0 + ko, &lds[3][rowb][0]);
      if (MODE == 1) {
        gld16(Ahp + (size_t)(m0 + row) * 1024 + k0 + ko, &lds[0][rowb][0]);
        gld16(Alp + (size_t)(m0 + row) * 1024 + k0 + ko, &lds[1][rowb][0]);
      }
    }
    if (MODE == 0) {
      const int r_ = tid >> 4, c4 = (tid & 15) << 2;
#pragma unroll
      for (int v = 0; v < 8; ++v) {
        const int row = (v << 4) + r_;
        const float xs[4] = {areg[v].x, areg[v].y, areg[v].z, areg[v].w};
        uint2 hv, lv;
        hv.x = (u32)bft(xs[0]) | ((u32)bft(xs[1]) << 16);
        hv.y = (u32)bft(xs[2]) | ((u32)bft(xs[3]) << 16);
        lv.x = (u32)bft(xs[0] - bfh(xs[0])) | ((u32)bft(xs[1] - bfh(xs[1])) << 16);
        lv.y = (u32)bft(xs[2] - bfh(xs[2])) | ((u32)bft(xs[3] - bfh(xs[3])) << 16);
        const int phys = (((c4 >> 3) ^ (row & 7)) << 3) + (c4 & 7);
        *(uint2*)&lds[0][row][phys] = hv;
        *(uint2*)&lds[1][row][phys] = lv;
      }
    }
    __syncthreads();
#pragma unroll
    for (int kk = 0; kk < 2; ++kk) {
      short8 fah[4], fal[4], fbh[4], fbl[4];
#pragma unroll
      for (int f = 0; f < 4; ++f) {
        const int ar = (wr << 6) + (f << 4) + (l & 15);
        const int ac = (((kk << 2) + (l >> 4)) ^ (ar & 7)) << 3;
        fah[f] = *(const short8*)&lds[0][ar][ac];
        fal[f] = *(const short8*)&lds[1][ar][ac];
        const int br = (wc << 6) + (f << 4) + (l & 15);
        const int bc = (((kk << 2) + (l >> 4)) ^ (br & 7)) << 3;
        fbh[f] = *(const short8*)&lds[2][br][bc];
        fbl[f] = *(const short8*)&lds[3][br][bc];
      }
#pragma unroll
      for (int fm = 0; fm < 4; ++fm)
#pragma unroll
        for (int fn = 0; fn < 4; ++fn) {
          acc[fm][fn] = __builtin_amdgcn_mfma_f32_16x16x32_bf16(fah[fm], fbh[fn], acc[fm][fn], 0, 0, 0);
          acc[fm][fn] = __builtin_amdgcn_mfma_f32_16x16x32_bf16(fah[fm], fbl[fn], acc[fm][fn], 0, 0, 0);
          acc[fm][fn] = __builtin_amdgcn_mfma_f32_16x16x32_bf16(fal[fm], fbh[fn], acc[fm][fn], 0, 0, 0);
        }
    }
  }

#pragma unroll
  for (int fm = 0; fm < 4; ++fm)
#pragma unroll
    for (int fn = 0; fn < 4; ++fn) {
      const int n = n0 + (wc << 6) + (fn << 4) + (l & 15);
#pragma unroll
      for (int j = 0; j < 4; ++j) {
        const int m = m0 + (wr << 6) + (fm << 4) + ((l >> 4) << 2) + j;
        const float v = acc[fm][fn][j];
        if (MODE == 0) {
          const int qq = m >> 3, b = m & 7;
          const int s = n >> 10, hd = (n >> 6) & 15, dh = n & 63;
          u16* dst = (u16*)ws + ((s == 0) ? UO_QF : (s == 1) ? UO_KF : UO_VF);
          dst[((((b << 4) + hd) << 10) + qq) * 64 + swz(qq, dh)] = f16b(v);
        } else {
          ws[OFF_TMP + (size_t)m * 1024 + n] = v + resid[(size_t)m * 1024 + n];
        }
      }
    }
}

// ---------------- r @ Wr -> RKEF16 (reversed, padded, swizzled f16) ----------------
__global__ __launch_bounds__(256) void k_proj_r(const float* __restrict__ Rm,
                                                const float* __restrict__ Br,
                                                float* __restrict__ ws) {
  const int bx = blockIdx.x, by = blockIdx.y;
  const int m0 = by * 128, n0 = bx * 128;
  __shared__ float AsT[16][132];
  __shared__ float Bs[16][132];
  const int tid = threadIdx.x;
  const int ty = tid >> 4, tx = tid & 15;
  const int a_row = tid >> 2, a_kc = (tid & 3) << 2;
  const int b_k = tid >> 5, b_col = (tid & 31) << 2;

  float acc[2][2][4][4];
#pragma unroll
  for (int p = 0; p < 2; ++p)
#pragma unroll
    for (int q = 0; q < 2; ++q)
#pragma unroll
      for (int i = 0; i < 4; ++i)
#pragma unroll
        for (int j = 0; j < 4; ++j) acc[p][q][i][j] = 0.f;

  for (int k0 = 0; k0 < 1024; k0 += 16) {
    float4 av0 = *(const float4*)&Rm[(size_t)(m0 + a_row) * 1024 + k0 + a_kc];
    float4 av1 = *(const float4*)&Rm[(size_t)(m0 + a_row + 64) * 1024 + k0 + a_kc];
    float4 bv0 = *(const float4*)&Br[(size_t)(k0 + b_k) * 1024 + n0 + b_col];
    float4 bv1 = *(const float4*)&Br[(size_t)(k0 + b_k + 8) * 1024 + n0 + b_col];
    __syncthreads();
    AsT[a_kc + 0][a_row] = av0.x;  AsT[a_kc + 1][a_row] = av0.y;
    AsT[a_kc + 2][a_row] = av0.z;  AsT[a_kc + 3][a_row] = av0.w;
    AsT[a_kc + 0][a_row + 64] = av1.x;  AsT[a_kc + 1][a_row + 64] = av1.y;
    AsT[a_kc + 2][a_row + 64] = av1.z;  AsT[a_kc + 3][a_row + 64] = av1.w;
    *(float4*)&Bs[b_k][b_col] = bv0;
    *(float4*)&Bs[b_k + 8][b_col] = bv1;
    __syncthreads();
#pragma unroll
    for (int k = 0; k < 16; ++k) {
      float4 a0 = *(const float4*)&AsT[k][ty << 2];
      float4 a1 = *(const float4*)&AsT[k][64 + (ty << 2)];
      float4 b0 = *(const float4*)&Bs[k][tx << 2];
      float4 b1 = *(const float4*)&Bs[k][64 + (tx << 2)];
      float aa[2][4] = {{a0.x, a0.y, a0.z, a0.w}, {a1.x, a1.y, a1.z, a1.w}};
      float bb[2][4] = {{b0.x, b0.y, b0.z, b0.w}, {b1.x, b1.y, b1.z, b1.w}};
#pragma unroll
      for (int p = 0; p < 2; ++p)
#pragma unroll
        for (int q = 0; q < 2; ++q)
#pragma unroll
          for (int i = 0; i < 4; ++i)
#pragma unroll
            for (int j = 0; j < 4; ++j)
              acc[p][q][i][j] += aa[p][i] * bb[q][j];
    }
  }
  u16* rkef = (u16*)ws + UO_RKEF;
#pragma unroll
  for (int p = 0; p < 2; ++p)
#pragma unroll
    for (int q = 0; q < 2; ++q) {
      const int cbase = n0 + (q << 6) + (tx << 2);
      const int nn = (cbase >> 6) & 15, dh0 = cbase & 63;
#pragma unroll
      for (int i = 0; i < 4; ++i) {
        const int m = m0 + (p << 6) + (ty << 2) + i;
        const int g = 1087 - m;  // padded row: (1023-m)+64
#pragma unroll
        for (int e = 0; e < 4; ++e)
          rkef[(nn * 1152 + g) * 64 + swz(g, dh0 + e)] = f16b(acc[p][q][i][e]);
      }
    }
}

// ---------------- V^T f16 (pre-swizzled): VF16 [j][dh] -> VT16 [dh][j] ----------------
__global__ __launch_bounds__(256) void k_vt(float* __restrict__ ws) {
  const u16* vf = (const u16*)ws + UO_VF;
  u16* vt = (u16*)ws + UO_VT;
  __shared__ u16 ld[64][72];
  const int bn = blockIdx.x, jt = blockIdx.y;
  const int j0 = jt << 6, tid = threadIdx.x;
  const int r = tid >> 4, q4 = (tid & 15) << 2;
#pragma unroll
  for (int rep = 0; rep < 4; ++rep) {
    const int j = (rep << 4) + r;
    uint2 v = *(const uint2*)&vf[(size_t)(((bn << 10) + j0 + j) << 6) + q4];
    const int dh0 = (((q4 >> 3) ^ (j & 7)) << 3) + (q4 & 7);
    ld[dh0 + 0][j] = (u16)(v.x & 0xffff);
    ld[dh0 + 1][j] = (u16)(v.x >> 16);
    ld[dh0 + 2][j] = (u16)(v.y & 0xffff);
    ld[dh0 + 3][j] = (u16)(v.y >> 16);
  }
  __syncthreads();
#pragma unroll
  for (int rep = 0; rep < 4; ++rep) {
    const int dh = (rep << 4) + r;
    const int lj = (((q4 >> 3) ^ (dh & 7)) << 3) + (q4 & 7);
    uint2 o;
    o.x = (u32)ld[dh][lj + 0] | ((u32)ld[dh][lj + 1] << 16);
    o.y = (u32)ld[dh][lj + 2] | ((u32)ld[dh][lj + 3] << 16);
    *(uint2*)&vt[(size_t)(((bn << 6) + dh) << 10) + j0 + q4] = o;
  }
}

// ---------------- bias dots (reads f16) + pad zero-fill ----------------
__global__ __launch_bounds__(256) void k_bias(const float* __restrict__ rwb,
                                              const float* __restrict__ rrb,
                                              float* __restrict__ ws) {
  const int t = blockIdx.x * 256 + threadIdx.x;
  const u16* kf = (const u16*)ws + UO_KF;
  u16* rkef = (u16*)ws + UO_RKEF;
  if (t < 131072) {                       // bk[b,n,j]
    const int j = t & 1023, bn = t >> 10, n = bn & 15;
    const u16* row = kf + ((((size_t)bn << 10) + j) << 6);
    const float* br = rwb + (n << 6);
    float s = 0.f;
#pragma unroll
    for (int pc = 0; pc < 8; ++pc) {
      const int lb = ((pc ^ (j & 7)) << 3);
#pragma unroll
      for (int e = 0; e < 8; ++e) s += f16f(row[pc * 8 + e]) * br[lb + e];
    }
    ws[OFF_BK + t] = s;
  } else if (t < 147456) {                // brd[n,d]
    const int u = t - 131072;
    const int d = u & 1023, n = u >> 10, p = d + 64;
    const u16* row = (const u16*)ws + UO_RKEF + (n * 1152 + p) * 64;
    const float* br = rrb + (n << 6);
    float s = 0.f;
#pragma unroll
    for (int pc = 0; pc < 8; ++pc) {
      const int lb = ((pc ^ (p & 7)) << 3);
#pragma unroll
      for (int e = 0; e < 8; ++e) s += f16f(row[pc * 8 + e]) * br[lb + e];
    }
    ws[OFF_BRD + n * 1088 + 64 + d] = s;
  } else if (t < 148480) {                // BRD front pad zeros
    const int u = t - 147456;
    ws[OFF_BRD + (u >> 6) * 1088 + (u & 63)] = 0.f;
  } else if (t < 181248) {                // RKEF16 pad rows zero (p<64, p>=1088)
    const int u = t - 148480;
    const int n = u >> 11, pi = u & 2047;
    const int rp = pi >> 4, c4 = (pi & 15) << 2;
    const int p = (rp < 64) ? rp : (1024 + rp);
    *(uint2*)&rkef[(n * 1152 + p) * 64 + c4] = make_uint2(0u, 0u);
  }
}

// ---------------- f16 MFMA flash attention, lean inner loop ----------------
__global__ __launch_bounds__(256) void k_attn(float* __restrict__ ws) {
  __shared__ __align__(16) u16 Qf[4096];
  __shared__ __align__(16) u16 pool[17408];
  // ph1: K [0,4096), band [4096,12288), VT [13312,17408)
  // ph2: T f16 [64][136] [0,8704), Pf [64][72] [8704,13312)
  const int tid = threadIdx.x, wv = tid >> 6, l = tid & 63;
  const int bn = blockIdx.x, it = 15 - blockIdx.y;       // heavy-first
  const int b = bn >> 4, n = bn & 15, i0 = it << 6;
  const u16* QF = (const u16*)ws + UO_QF + ((size_t)bn << 16);
  const u16* KF = (const u16*)ws + UO_KF + ((size_t)bn << 16);
  const u16* VT = (const u16*)ws + UO_VT + ((size_t)bn << 16);
  const u16* RK = (const u16*)ws + UO_RKEF + n * 73728;
  const float* BKp = ws + OFF_BK + (bn << 10);
  const float* BRD = ws + OFF_BRD + n * 1088;

  const int lg = l >> 4, lc = l & 15;
  const int rown = (wv << 4) + (lg << 2);
  const int sr8 = l >> 3, sc8 = (l & 7) << 3;

  // stage Q once (drained by first in-loop barrier)
#pragma unroll
  for (int i = 0; i < 2; ++i) {
    const int rb = (wv << 4) + (i << 3);
    gld16(QF + (((size_t)(i0 + rb + sr8)) << 6) + sc8, &Qf[rb << 6]);
  }

  f32x4 oacc[4];
  float m_r[4], l_r[4];
#pragma unroll
  for (int j = 0; j < 4; ++j) {
    m_r[j] = -3.0e38f; l_r[j] = 0.f;
    oacc[j] = (f32x4){0.f, 0.f, 0.f, 0.f};
  }

  for (int jt = 0; jt <= it; ++jt) {
    const int j0 = jt << 6, dbase = i0 - j0;
    __syncthreads();  // sync0: pool free (prev PV reads done)

    // stage K(2) + band(4) + V^T(2): pure global_load_lds, verbatim rows
#pragma unroll
    for (int i = 0; i < 2; ++i) {
      const int rb = (wv << 4) + (i << 3);
      gld16(KF + (((size_t)(j0 + rb + sr8)) << 6) + sc8, &pool[rb << 6]);
    }
#pragma unroll
    for (int i = 0; i < 4; ++i) {
      const int rb = (wv << 5) + (i << 3);
      const int p = dbase + 1 + rb + sr8;
      gld16(RK + ((size_t)p << 6) + sc8, &pool[4096 + (rb << 6)]);
    }
#pragma unroll
    for (int i = 0; i < 2; ++i) {
      const int rb = (wv << 4) + (i << 3);
      gld16(VT + (((size_t)(rb + sr8)) << 10) + j0 + sc8, &pool[13312 + (rb << 6)]);
    }
    __syncthreads();  // sync1: staged

    // AC (Q@K^T) + T (Q@band^T) MFMA
    f32x4 sacc[4], tacc[8];
#pragma unroll
    for (int f = 0; f < 4; ++f) sacc[f] = (f32x4){0.f, 0.f, 0.f, 0.f};
#pragma unroll
    for (int f = 0; f < 8; ++f) tacc[f] = (f32x4){0.f, 0.f, 0.f, 0.f};
    const int ar = (wv << 4) + lc;
#pragma unroll
    for (int kk = 0; kk < 2; ++kk) {
      const int ch = (kk << 2) + lg;
      f16x8 af = *(const f16x8*)&Qf[(ar << 6) + ((ch ^ (ar & 7)) << 3)];
#pragma unroll
      for (int fc = 0; fc < 4; ++fc) {
        const int br = (fc << 4) + lc;
        f16x8 bf = *(const f16x8*)&pool[(br << 6) + ((ch ^ (br & 7)) << 3)];
        sacc[fc] = __builtin_amdgcn_mfma_f32_16x16x32_f16(af, bf, sacc[fc], 0, 0, 0);
      }
#pragma unroll
      for (int fc = 0; fc < 8; ++fc) {
        const int br = (fc << 4) + lc;
        f16x8 bf = *(const f16x8*)&pool[4096 + (br << 6) + ((ch ^ ((br + 1) & 7)) << 3)];
        tacc[fc] = __builtin_amdgcn_mfma_f32_16x16x32_f16(af, bf, tacc[fc], 0, 0, 0);
      }
    }
    __syncthreads();  // sync2: K/band reads done, pool[0,13312) reusable

    // T-write (f16 [64][136], +brd), wave-local rows
    u16* T = pool;
#pragma unroll
    for (int fc = 0; fc < 8; ++fc) {
      const int col = (fc << 4) + lc;
      const float brd_v = (dbase + col < 1087) ? BRD[1 + dbase + col] : 0.f;
#pragma unroll
      for (int j = 0; j < 4; ++j)
        T[(rown + j) * 136 + col] = f16b(tacc[fc][j] + brd_v);
    }

    // gather rel-shift + biases + mask -> S
    float S[4][4];
#pragma unroll
    for (int fc = 0; fc < 4; ++fc) {
      const int cj = (fc << 4) + lc;
      const float bkv = BKp[j0 + cj];
#pragma unroll
      for (int j = 0; j < 4; ++j) {
        const int ri = rown + j;
        const float t = f16f(T[ri * 136 + (ri - cj + 63)]);
        float s = 0.125f * (sacc[fc][j] + bkv + t);
        if (dbase == 0 && ri < cj) s = -1.0e30f;
        S[fc][j] = s;
      }
    }

    // online softmax (per-row j; per-component rescale)
    u16* Pf = pool + 8704;
#pragma unroll
    for (int j = 0; j < 4; ++j) {
      float mt = fmaxf(fmaxf(S[0][j], S[1][j]), fmaxf(S[2][j], S[3][j]));
      mt = fmaxf(mt, __shfl_xor(mt, 1));
      mt = fmaxf(mt, __shfl_xor(mt, 2));
      mt = fmaxf(mt, __shfl_xor(mt, 4));
      mt = fmaxf(mt, __shfl_xor(mt, 8));
      const float mnew = fmaxf(m_r[j], mt);
      const float sc = __expf(m_r[j] - mnew);
      m_r[j] = mnew;
      float rs = 0.f;
#pragma unroll
      for (int fc = 0; fc < 4; ++fc) {
        const float p = __expf(S[fc][j] - mnew);
        rs += p;
        Pf[(rown + j) * 72 + (fc << 4) + lc] = f16b(p);
      }
      rs += __shfl_xor(rs, 1);
      rs += __shfl_xor(rs, 2);
      rs += __shfl_xor(rs, 4);
      rs += __shfl_xor(rs, 8);
      l_r[j] = l_r[j] * sc + rs;
#pragma unroll
      for (int fc = 0; fc < 4; ++fc) oacc[fc][j] *= sc;   // per-row
    }

    // PV MFMA (Pf wave-local, VT staged since sync1)
    const int pr = (wv << 4) + lc;
#pragma unroll
    for (int kk = 0; kk < 2; ++kk) {
      const int ch = (kk << 2) + lg;
      f16x8 pa = *(const f16x8*)&Pf[pr * 72 + (ch << 3)];
#pragma unroll
      for (int fc = 0; fc < 4; ++fc) {
        const int vr = (fc << 4) + lc;
        f16x8 vb = *(const f16x8*)&pool[13312 + (vr << 6) + ((ch ^ (vr & 7)) << 3)];
        oacc[fc] = __builtin_amdgcn_mfma_f32_16x16x32_f16(pa, vb, oacc[fc], 0, 0, 0);
      }
    }
  }

  // epilogue: normalize, write attn_vec as bf16 hi/lo
  u16* const avh = (u16*)ws + UO_AVH;
  u16* const avl = (u16*)ws + UO_AVL;
#pragma unroll
  for (int j = 0; j < 4; ++j) {
    const float inv = 1.f / l_r[j];
    const int i = i0 + rown + j;
#pragma unroll
    for (int fc = 0; fc < 4; ++fc) {
      const int dh = (fc << 4) + lc;
      const float val = oacc[fc][j] * inv;
      const size_t idx = (((size_t)(i << 3) + b) << 10) + (n << 6) + dh;
      avh[idx] = bft(val);
      avl[idx] = bft(val - bfh(val));
    }
  }
}

// ---------------- LayerNorm ----------------
__global__ __launch_bounds__(256) void k_ln(const float* __restrict__ x,
                                            const float* __restrict__ g,
                                            const float* __restrict__ bb,
                                            float* __restrict__ out) {
  const int row = blockIdx.x;
  const int tid = threadIdx.x;
  float4 v = *(const float4*)&x[(size_t)row * 1024 + (tid << 2)];
  float s = v.x + v.y + v.z + v.w;
  float q = v.x * v.x + v.y * v.y + v.z * v.z + v.w * v.w;
#pragma unroll
  for (int off = 1; off < 64; off <<= 1) {
    s += __shfl_xor(s, off);
    q += __shfl_xor(q, off);
  }
  __shared__ float ss[4], sq[4];
  if ((tid & 63) == 0) { ss[tid >> 6] = s; sq[tid >> 6] = q; }
  __syncthreads();
  const float S = ss[0] + ss[1] + ss[2] + ss[3];
  const float Q = sq[0] + sq[1] + sq[2] + sq[3];
  const float mu = S * (1.f / 1024.f);
  const float var = Q * (1.f / 1024.f) - mu * mu;
  const float rstd = rsqrtf(var + 1e-5f);
  float4 gv = *(const float4*)&g[tid << 2];
  float4 bv = *(const float4*)&bb[tid << 2];
  float4 o = make_float4((v.x - mu) * rstd * gv.x + bv.x,
                         (v.y - mu) * rstd * gv.y + bv.y,
                         (v.z - mu) * rstd * gv.z + bv.z,
                         (v.w - mu) * rstd * gv.w + bv.w);
  *(float4*)&out[(size_t)row * 1024 + (tid << 2)] = o;
}

// ---------------------------------------------------------------------------
extern "C" void kernel_launch(void* const* d_in, const int* in_sizes, int n_in,
                              void* d_out, int out_size, void* d_ws, size_t ws_size,
                              hipStream_t stream) {
  const float* w    = (const float*)d_in[0];
  const float* r    = (const float*)d_in[1];
  const float* rwb  = (const float*)d_in[2];
  const float* rrb  = (const float*)d_in[3];
  const float* Wqkv = (const float*)d_in[4];
  const float* Wr   = (const float*)d_in[5];
  const float* Wo   = (const float*)d_in[6];
  const float* lng  = (const float*)d_in[7];
  const float* lnb  = (const float*)d_in[8];
  float* out = (float*)d_out;
  float* ws  = (float*)d_ws;
  u16* const wqth = (u16*)ws + UO_WQTH;
  u16* const wqtl = (u16*)ws + UO_WQTL;
  u16* const woth = (u16*)ws + UO_WOTH;
  u16* const wotl = (u16*)ws + UO_WOTL;
  const u16* const avh = (const u16*)ws + UO_AVH;
  const u16* const avl = (const u16*)ws + UO_AVL;

  k_convT<<<768, 256, 0, stream>>>(Wqkv, 3072, wqth, wqtl);
  k_gemm<0><<<dim3(24, 64), 256, 0, stream>>>(w, nullptr, nullptr, wqth, wqtl, nullptr, ws);
  k_proj_r<<<dim3(8, 8), 256, 0, stream>>>(r, Wr, ws);
  k_vt<<<dim3(128, 16), 256, 0, stream>>>(ws);
  k_bias<<<708, 256, 0, stream>>>(rwb, rrb, ws);
  k_attn<<<dim3(128, 16), 256, 0, stream>>>(ws);
  k_convT<<<256, 256, 0, stream>>>(Wo, 1024, woth, wotl);
  k_gemm<1><<<dim3(8, 64), 256, 0, stream>>>(nullptr, avh, avl, woth, wotl, w, ws);
  k_ln<<<8192, 256, 0, stream>>>(ws, lng, lnb, out);
}